// Round 2
// baseline (633.877 us; speedup 1.0000x reference)
//
#include <hip/hip_runtime.h>

typedef unsigned short u16;
typedef unsigned int   u32;
typedef __attribute__((ext_vector_type(8))) short short8;
typedef __attribute__((ext_vector_type(4))) float f32x4;

__device__ inline float bf2f(u32 bits16) {
    union { u32 u; float f; } c; c.u = bits16 << 16; return c.f;
}
__device__ inline u16 f2bf(float f) {
    union { float f; u32 u; } c; c.f = f;
    u32 u = c.u;
    u32 r = (u + 0x7fffu + ((u >> 16) & 1u)) >> 16;
    return (u16)r;
}

// ---------------- runtime dtype detection ----------------
// flags[0]: 1 => float inputs are fp32, 0 => bf16
// flags[1]: constant 0 (bf16) — used as the "ff" for internal bf16 GEMM inputs
// flags[2]: 1 => edge_index is int64, 0 => int32
__global__ void detect_kernel(const u32* xw, const int* ebuf_int, int* flags) {
    __shared__ int cnt;
    if (threadIdx.x == 0) cnt = 0;
    __syncthreads();
    u32 w = xw[threadIdx.x];
    int e = (int)((w >> 7) & 0xffu);   // bf16-pair: exponent of low element
    if (e >= 110 && e <= 145) atomicAdd(&cnt, 1);
    int ev = ebuf_int[2 * threadIdx.x + 1];   // odd int32 words
    unsigned long long any = __ballot(ev != 0);  // wave 0 covers words 1..127
    __syncthreads();
    if (threadIdx.x == 0) {
        flags[0] = (cnt < 192) ? 1 : 0;
        flags[1] = 0;
        flags[2] = (any == 0ULL) ? 1 : 0;
    }
}

__global__ void convert_kernel(const void* ebuf, const int* flags,
                               int* src, int* dst, int E) {
    int i = blockIdx.x * 256 + threadIdx.x;
    if (i >= 2 * E) return;
    int v;
    if (flags[2]) v = (int)((const long long*)ebuf)[i];
    else          v = ((const int*)ebuf)[i];
    if (i < E) src[i] = v; else dst[i - E] = v;
}

// ---------------- degree / dinv ----------------
__global__ void deg_kernel(const int* dst, int* deg, int E) {
    int e = blockIdx.x * 256 + threadIdx.x;
    if (e >= E) return;
    atomicAdd(&deg[dst[e]], 1);
}

__global__ void dinv_kernel(const int* deg, float* dinv, int N) {
    int i = blockIdx.x * 256 + threadIdx.x;
    if (i >= N) return;
    int d = deg[i];
    dinv[i] = (d > 0) ? 1.0f / sqrtf((float)d) : 0.0f;
}

// ---------------- bias convert to fp32 ----------------
__global__ void bconv_kernel(const void* b1, const void* b2, const int* flags,
                             float* b1f, float* b2f, int HID, int CLS) {
    int i = blockIdx.x * 256 + threadIdx.x;
    int f = flags[0];
    if (i < HID) b1f[i] = f ? ((const float*)b1)[i] : bf2f(((const u16*)b1)[i]);
    if (i < CLS) b2f[i] = f ? ((const float*)b2)[i] : bf2f(((const u16*)b2)[i]);
}

// ---------------- exclusive scan (3 kernels) ----------------
__device__ inline int wave_incl_scan(int v, int lane) {
    #pragma unroll
    for (int d = 1; d < 64; d <<= 1) {
        int t = __shfl_up(v, d, 64);
        if (lane >= d) v += t;
    }
    return v;
}

__global__ void scan_block_kernel(const int* deg, int* row_start, int* bsums, int N) {
    __shared__ int wsum[4];
    int t = threadIdx.x, lane = t & 63, wv = t >> 6;
    int i = blockIdx.x * 256 + t;
    int v = (i < N) ? deg[i] : 0;
    int inc = wave_incl_scan(v, lane);
    if (lane == 63) wsum[wv] = inc;
    __syncthreads();
    int off = 0;
    #pragma unroll
    for (int w = 0; w < 4; ++w) if (w < wv) off += wsum[w];
    if (i < N) row_start[i] = off + inc - v;
    if (t == 255) bsums[blockIdx.x] = off + inc;
}

__global__ void scan_sums_kernel(int* bsums, int nb) {
    __shared__ int wsum[8];
    int t = threadIdx.x, lane = t & 63, wv = t >> 6;
    int v = (t < nb) ? bsums[t] : 0;
    int inc = wave_incl_scan(v, lane);
    if (lane == 63) wsum[wv] = inc;
    __syncthreads();
    int off = 0;
    #pragma unroll
    for (int w = 0; w < 8; ++w) if (w < wv) off += wsum[w];
    if (t < nb) bsums[t] = off + inc - v;   // exclusive
}

__global__ void scan_add_kernel(int* row_start, const int* bsums, int N, int E) {
    int i = blockIdx.x * 256 + threadIdx.x;
    if (i < N) row_start[i] += bsums[blockIdx.x];
    if (blockIdx.x == 0 && threadIdx.x == 0) row_start[N] = E;
}

// ---------------- CSR fill ----------------
__global__ void fill_kernel(const int* src, const int* dst, const int* row_start,
                            int* cursor, int* csr, int E) {
    int e = blockIdx.x * 256 + threadIdx.x;
    if (e >= E) return;
    int d = dst[e];
    int slot = atomicAdd(&cursor[d], 1);
    csr[row_start[d] + slot] = src[e];
}

// ---------------- weight prepack into MFMA B-fragment layout ----------------
// pack index = ((nt*KT + kk)*64 + lane)*8 + j : element B[k][n],
// n = nt*16 + (lane&15), k = kk*32 + (lane>>4)*8 + j
template<int NT, int KT, int NCOLS>
__global__ void prepack_kernel(const void* W, const int* flags, u16* pack) {
    int p = blockIdx.x * 256 + threadIdx.x;
    constexpr int TOT = NT * KT * 64 * 8;
    if (p >= TOT) return;
    int j = p & 7, lane = (p >> 3) & 63, fk = p >> 9;
    int kk = fk % KT, nt = fk / KT;
    int n = nt * 16 + (lane & 15);
    int k = kk * 32 + (lane >> 4) * 8 + j;
    u16 v = flags[0] ? f2bf(((const float*)W)[k * NCOLS + n])
                     : ((const u16*)W)[k * NCOLS + n];
    pack[p] = v;
}

// ---------------- GEMM: A[M,K] (fp32 or bf16 per *ff) x Bpack -> C bf16 ----
template<int NT, int KT>
__global__ __launch_bounds__(256)
void gemm_kernel(const void* __restrict__ A, const int* __restrict__ ff,
                 const u16* __restrict__ Bpack, u16* __restrict__ C, int M) {
    constexpr int K = KT * 32;
    constexpr int Ncols = NT * 16;
    __shared__ short8 lds[NT * KT * 64];
    for (int i = threadIdx.x; i < NT * KT * 64; i += 256)
        lds[i] = ((const short8*)Bpack)[i];
    bool fA = (*ff != 0);
    __syncthreads();
    int wave = threadIdx.x >> 6, lane = threadIdx.x & 63;
    int m0 = (blockIdx.x * 4 + wave) * 16;
    if (m0 >= M) return;
    int q = lane >> 4;
    int row = m0 + (lane & 15);
    f32x4 acc[NT];
    #pragma unroll
    for (int nt = 0; nt < NT; ++nt) acc[nt] = (f32x4){0.f, 0.f, 0.f, 0.f};
    #pragma unroll
    for (int kk = 0; kk < KT; ++kk) {
        short8 a;
        if (fA) {
            const float* Af = (const float*)A + (size_t)row * K + kk * 32 + q * 8;
            f32x4 v0 = ((const f32x4*)Af)[0];
            f32x4 v1 = ((const f32x4*)Af)[1];
            union { short8 s; u16 u[8]; } pa;
            pa.u[0] = f2bf(v0[0]); pa.u[1] = f2bf(v0[1]);
            pa.u[2] = f2bf(v0[2]); pa.u[3] = f2bf(v0[3]);
            pa.u[4] = f2bf(v1[0]); pa.u[5] = f2bf(v1[1]);
            pa.u[6] = f2bf(v1[2]); pa.u[7] = f2bf(v1[3]);
            a = pa.s;
        } else {
            a = ((const short8*)((const u16*)A + (size_t)row * K))[kk * 4 + q];
        }
        #pragma unroll
        for (int nt = 0; nt < NT; ++nt) {
            short8 b = lds[(nt * KT + kk) * 64 + lane];
            acc[nt] = __builtin_amdgcn_mfma_f32_16x16x32_bf16(a, b, acc[nt], 0, 0, 0);
        }
    }
    #pragma unroll
    for (int nt = 0; nt < NT; ++nt) {
        int col = nt * 16 + (lane & 15);
        #pragma unroll
        for (int r = 0; r < 4; ++r) {
            int rrow = m0 + q * 4 + r;
            C[(size_t)rrow * Ncols + col] = f2bf(acc[nt][r]);
        }
    }
}

// ---------------- layer-1 aggregation: gather by dst, +bias, relu ----------------
// one wave per node; lane owns features 2*lane, 2*lane+1 (HID=128); H bf16
__global__ __launch_bounds__(256)
void agg1_kernel(const u16* __restrict__ H, const int* __restrict__ csr,
                 const int* __restrict__ row_start, const float* __restrict__ dinv,
                 const float* __restrict__ b1f, u16* __restrict__ H1, int N) {
    int wave = threadIdx.x >> 6, lane = threadIdx.x & 63;
    int n = blockIdx.x * 4 + wave;
    if (n >= N) return;
    int s0 = row_start[n], s1 = row_start[n + 1];
    float acc0 = 0.f, acc1 = 0.f;
    const u32* H32 = (const u32*)H;
    for (int e = s0; e < s1; ++e) {
        int s = csr[e];
        float w = dinv[s];
        u32 hv = H32[(size_t)s * 64 + lane];
        acc0 += w * bf2f(hv & 0xffffu);
        acc1 += w * bf2f(hv >> 16);
    }
    float wn = dinv[n];
    float v0 = fmaxf(wn * acc0 + b1f[2 * lane], 0.f);
    float v1 = fmaxf(wn * acc1 + b1f[2 * lane + 1], 0.f);
    u32 outv = (u32)f2bf(v0) | ((u32)f2bf(v1) << 16);
    ((u32*)H1)[(size_t)n * 64 + lane] = outv;
}

// ---------------- layer-2 aggregation + bias + log_softmax ----------------
// one wave per node; lane&31 = class, two half-waves split the edge list
__global__ __launch_bounds__(256)
void agg2_kernel(const u16* __restrict__ H2, const int* __restrict__ csr,
                 const int* __restrict__ row_start, const float* __restrict__ dinv,
                 const float* __restrict__ b2f, const int* __restrict__ ff,
                 void* __restrict__ out, int N) {
    int wave = threadIdx.x >> 6, lane = threadIdx.x & 63;
    int n = blockIdx.x * 4 + wave;
    if (n >= N) return;
    int c = lane & 31, half = lane >> 5;
    int s0 = row_start[n], s1 = row_start[n + 1];
    float acc = 0.f;
    for (int e = s0 + half; e < s1; e += 2) {
        int s = csr[e];
        acc += dinv[s] * bf2f(H2[(size_t)s * 32 + c]);
    }
    acc += __shfl_xor(acc, 32);
    float tot = dinv[n] * acc + b2f[c];
    float mx = tot;
    #pragma unroll
    for (int m = 16; m; m >>= 1) mx = fmaxf(mx, __shfl_xor(mx, m));
    float ex = expf(tot - mx);
    float sm = ex;
    #pragma unroll
    for (int m = 16; m; m >>= 1) sm += __shfl_xor(sm, m);
    float r = tot - mx - logf(sm);
    if (half == 0) {
        if (*ff) ((float*)out)[(size_t)n * 32 + c] = r;
        else     ((u16*)out)[(size_t)n * 32 + c] = f2bf(r);
    }
}

extern "C" void kernel_launch(void* const* d_in, const int* in_sizes, int n_in,
                              void* d_out, int out_size, void* d_ws, size_t ws_size,
                              hipStream_t stream) {
    const void* x  = d_in[0];
    const void* W1 = d_in[1];
    const void* b1 = d_in[2];
    const void* W2 = d_in[3];
    const void* b2 = d_in[4];
    const void* eb = d_in[5];

    const int HID  = in_sizes[2];            // 128
    const int CLS  = in_sizes[4];            // 32
    const int FEAT = in_sizes[1] / HID;      // 256
    const int N    = in_sizes[0] / FEAT;     // 100000
    const int E    = in_sizes[5] / 2;        // 1600000
    (void)n_in; (void)out_size;

    char* w = (char*)d_ws;
    size_t p = 0;
    auto alloc = [&](size_t bytes) {
        size_t o = p; p = (p + bytes + 255) & ~(size_t)255; return o;
    };
    int*   flags     = (int*)  (w + alloc(32));
    size_t deg_off   =          alloc((size_t)N * 4);
    int*   deg       = (int*)  (w + deg_off);
    size_t cur_off   =          alloc((size_t)N * 4);
    int*   cursor    = (int*)  (w + cur_off);
    int*   row_start = (int*)  (w + alloc((size_t)(N + 1) * 4));
    int*   bsums     = (int*)  (w + alloc(512 * 4));
    int*   srcA      = (int*)  (w + alloc((size_t)E * 4));
    int*   dstA      = (int*)  (w + alloc((size_t)E * 4));
    int*   csr       = (int*)  (w + alloc((size_t)E * 4));
    float* dinv      = (float*)(w + alloc((size_t)N * 4));
    float* b1f       = (float*)(w + alloc((size_t)HID * 4));
    float* b2f       = (float*)(w + alloc((size_t)CLS * 4));
    u16*   B1p       = (u16*)  (w + alloc((size_t)FEAT * HID * 2));
    u16*   B2p       = (u16*)  (w + alloc((size_t)HID * CLS * 2));
    u16*   H         = (u16*)  (w + alloc((size_t)N * HID * 2));
    u16*   H1        = (u16*)  (w + alloc((size_t)N * HID * 2));
    u16*   H2        = (u16*)  (w + alloc((size_t)N * CLS * 2));
    if (p > ws_size) return;   // workspace too small: fail visibly

    detect_kernel<<<1, 256, 0, stream>>>((const u32*)x, (const int*)eb, flags);
    convert_kernel<<<(2 * E + 255) / 256, 256, 0, stream>>>(eb, flags, srcA, dstA, E);

    // deg + cursor zero (contiguous region)
    size_t zlen = (cur_off - deg_off) + (size_t)N * 4;
    hipMemsetAsync(deg, 0, zlen, stream);

    deg_kernel<<<(E + 255) / 256, 256, 0, stream>>>(dstA, deg, E);
    dinv_kernel<<<(N + 255) / 256, 256, 0, stream>>>(deg, dinv, N);
    bconv_kernel<<<1, 256, 0, stream>>>(b1, b2, flags, b1f, b2f, HID, CLS);

    int nb = (N + 255) / 256;
    scan_block_kernel<<<nb, 256, 0, stream>>>(deg, row_start, bsums, N);
    scan_sums_kernel<<<1, 512, 0, stream>>>(bsums, nb);
    scan_add_kernel<<<nb, 256, 0, stream>>>(row_start, bsums, N, E);

    fill_kernel<<<(E + 255) / 256, 256, 0, stream>>>(srcA, dstA, row_start, cursor, csr, E);

    prepack_kernel<8, 8, 128><<<(8 * 8 * 64 * 8 + 255) / 256, 256, 0, stream>>>(W1, flags, B1p);
    prepack_kernel<2, 4, 32><<<(2 * 4 * 64 * 8 + 255) / 256, 256, 0, stream>>>(W2, flags, B2p);

    int gblocks = (N + 63) / 64;
    gemm_kernel<8, 8><<<gblocks, 256, 0, stream>>>(x, flags, B1p, H, N);
    agg1_kernel<<<(N + 3) / 4, 256, 0, stream>>>(H, csr, row_start, dinv, b1f, H1, N);
    gemm_kernel<2, 4><<<gblocks, 256, 0, stream>>>(H1, flags + 1, B2p, H2, N);
    agg2_kernel<<<(N + 3) / 4, 256, 0, stream>>>(H2, csr, row_start, dinv, b2f, flags,
                                                 (void*)d_out, N);
}

// Round 3
// 467.667 us; speedup vs baseline: 1.3554x; 1.3554x over previous
//
#include <hip/hip_runtime.h>

typedef unsigned short u16;
typedef unsigned int   u32;
typedef __attribute__((ext_vector_type(8))) short short8;
typedef __attribute__((ext_vector_type(4))) float f32x4;

__device__ inline float bf2f(u32 bits16) {
    union { u32 u; float f; } c; c.u = bits16 << 16; return c.f;
}
__device__ inline u16 f2bf(float f) {
    union { float f; u32 u; } c; c.f = f;
    u32 u = c.u;
    u32 r = (u + 0x7fffu + ((u >> 16) & 1u)) >> 16;
    return (u16)r;
}

// ---------------- runtime dtype detection ----------------
// flags[0]: 1 => float inputs are fp32, 0 => bf16
// flags[1]: constant 0 — "ff" for internal bf16 GEMM inputs
// flags[2]: 1 => edge_index is int64, 0 => int32
__global__ void detect_kernel(const u32* xw, const int* ebuf_int, int* flags) {
    __shared__ int cnt;
    if (threadIdx.x == 0) cnt = 0;
    __syncthreads();
    u32 w = xw[threadIdx.x];
    int e = (int)((w >> 7) & 0xffu);   // bf16-pair: exponent of low element
    if (e >= 110 && e <= 145) atomicAdd(&cnt, 1);
    int ev = ebuf_int[2 * threadIdx.x + 1];
    unsigned long long any = __ballot(ev != 0);
    __syncthreads();
    if (threadIdx.x == 0) {
        flags[0] = (cnt < 192) ? 1 : 0;
        flags[1] = 0;
        flags[2] = (any == 0ULL) ? 1 : 0;
    }
}

// convert edges to int32 src/dst AND build degree histogram (deg pre-zeroed)
__global__ void convert_kernel(const void* ebuf, const int* flags,
                               int* src, int* dst, int* deg, int E) {
    int i = blockIdx.x * 256 + threadIdx.x;
    if (i >= 2 * E) return;
    int v;
    if (flags[2]) v = (int)((const long long*)ebuf)[i];
    else          v = ((const int*)ebuf)[i];
    if (i < E) src[i] = v;
    else { dst[i - E] = v; atomicAdd(&deg[v], 1); }
}

__global__ void dinv_kernel(const int* deg, float* dinv, int N) {
    int i = blockIdx.x * 256 + threadIdx.x;
    if (i >= N) return;
    int d = deg[i];
    dinv[i] = (d > 0) ? 1.0f / sqrtf((float)d) : 0.0f;
}

// ---------------- bias convert to fp32 ----------------
__global__ void bconv_kernel(const void* b1, const void* b2, const int* flags,
                             float* b1f, float* b2f, int HID, int CLS) {
    int i = blockIdx.x * 256 + threadIdx.x;
    int f = flags[0];
    if (i < HID) b1f[i] = f ? ((const float*)b1)[i] : bf2f(((const u16*)b1)[i]);
    if (i < CLS) b2f[i] = f ? ((const float*)b2)[i] : bf2f(((const u16*)b2)[i]);
}

// ---------------- exclusive scan (3 kernels) ----------------
__device__ inline int wave_incl_scan(int v, int lane) {
    #pragma unroll
    for (int d = 1; d < 64; d <<= 1) {
        int t = __shfl_up(v, d, 64);
        if (lane >= d) v += t;
    }
    return v;
}

__global__ void scan_block_kernel(const int* deg, int* row_start, int* bsums, int N) {
    __shared__ int wsum[4];
    int t = threadIdx.x, lane = t & 63, wv = t >> 6;
    int i = blockIdx.x * 256 + t;
    int v = (i < N) ? deg[i] : 0;
    int inc = wave_incl_scan(v, lane);
    if (lane == 63) wsum[wv] = inc;
    __syncthreads();
    int off = 0;
    #pragma unroll
    for (int w = 0; w < 4; ++w) if (w < wv) off += wsum[w];
    if (i < N) row_start[i] = off + inc - v;
    if (t == 255) bsums[blockIdx.x] = off + inc;
}

__global__ void scan_sums_kernel(int* bsums, int nb) {
    __shared__ int wsum[8];
    int t = threadIdx.x, lane = t & 63, wv = t >> 6;
    int v = (t < nb) ? bsums[t] : 0;
    int inc = wave_incl_scan(v, lane);
    if (lane == 63) wsum[wv] = inc;
    __syncthreads();
    int off = 0;
    #pragma unroll
    for (int w = 0; w < 8; ++w) if (w < wv) off += wsum[w];
    if (t < nb) bsums[t] = off + inc - v;   // exclusive
}

__global__ void scan_add_kernel(int* row_start, const int* bsums, int N, int E) {
    int i = blockIdx.x * 256 + threadIdx.x;
    if (i < N) row_start[i] += bsums[blockIdx.x];
    if (blockIdx.x == 0 && threadIdx.x == 0) row_start[N] = E;
}

// ---------------- CSR fill ----------------
__global__ void fill_kernel(const int* src, const int* dst, const int* row_start,
                            int* cursor, int* csr, int E) {
    int e = blockIdx.x * 256 + threadIdx.x;
    if (e >= E) return;
    int d = dst[e];
    int slot = atomicAdd(&cursor[d], 1);
    csr[row_start[d] + slot] = src[e];
}

// ---------------- weight prepack into MFMA B-fragment layout ----------------
template<int NT, int KT, int NCOLS>
__global__ void prepack_kernel(const void* W, const int* flags, u16* pack) {
    int p = blockIdx.x * 256 + threadIdx.x;
    constexpr int TOT = NT * KT * 64 * 8;
    if (p >= TOT) return;
    int j = p & 7, lane = (p >> 3) & 63, fk = p >> 9;
    int kk = fk % KT, nt = fk / KT;
    int n = nt * 16 + (lane & 15);
    int k = kk * 32 + (lane >> 4) * 8 + j;
    u16 v = flags[0] ? f2bf(((const float*)W)[k * NCOLS + n])
                     : ((const u16*)W)[k * NCOLS + n];
    pack[p] = v;
}

// ---- GEMM: A[M,K] (fp32/bf16 per *ff) x Bpack -> C bf16, rows scaled by dinv ----
template<int NT, int KT>
__global__ __launch_bounds__(256)
void gemm_kernel(const void* __restrict__ A, const int* __restrict__ ff,
                 const u16* __restrict__ Bpack, const float* __restrict__ dinv,
                 u16* __restrict__ C, int M) {
    constexpr int K = KT * 32;
    constexpr int Ncols = NT * 16;
    __shared__ short8 lds[NT * KT * 64];
    for (int i = threadIdx.x; i < NT * KT * 64; i += 256)
        lds[i] = ((const short8*)Bpack)[i];
    bool fA = (*ff != 0);
    __syncthreads();
    int wave = threadIdx.x >> 6, lane = threadIdx.x & 63;
    int m0 = (blockIdx.x * 4 + wave) * 16;
    if (m0 >= M) return;
    int q = lane >> 4;
    int row = m0 + (lane & 15);
    f32x4 acc[NT];
    #pragma unroll
    for (int nt = 0; nt < NT; ++nt) acc[nt] = (f32x4){0.f, 0.f, 0.f, 0.f};
    #pragma unroll
    for (int kk = 0; kk < KT; ++kk) {
        short8 a;
        if (fA) {
            const float* Af = (const float*)A + (size_t)row * K + kk * 32 + q * 8;
            f32x4 v0 = ((const f32x4*)Af)[0];
            f32x4 v1 = ((const f32x4*)Af)[1];
            union { short8 s; u16 u[8]; } pa;
            pa.u[0] = f2bf(v0[0]); pa.u[1] = f2bf(v0[1]);
            pa.u[2] = f2bf(v0[2]); pa.u[3] = f2bf(v0[3]);
            pa.u[4] = f2bf(v1[0]); pa.u[5] = f2bf(v1[1]);
            pa.u[6] = f2bf(v1[2]); pa.u[7] = f2bf(v1[3]);
            a = pa.s;
        } else {
            a = ((const short8*)((const u16*)A + (size_t)row * K))[kk * 4 + q];
        }
        #pragma unroll
        for (int nt = 0; nt < NT; ++nt) {
            short8 b = lds[(nt * KT + kk) * 64 + lane];
            acc[nt] = __builtin_amdgcn_mfma_f32_16x16x32_bf16(a, b, acc[nt], 0, 0, 0);
        }
    }
    float sc[4];
    #pragma unroll
    for (int r = 0; r < 4; ++r) sc[r] = dinv[m0 + q * 4 + r];
    #pragma unroll
    for (int nt = 0; nt < NT; ++nt) {
        int col = nt * 16 + (lane & 15);
        #pragma unroll
        for (int r = 0; r < 4; ++r) {
            int rrow = m0 + q * 4 + r;
            C[(size_t)rrow * Ncols + col] = f2bf(acc[nt][r] * sc[r]);
        }
    }
}

// ---- layer-1 aggregation: H rows pre-scaled by dinv[src]; +bias, relu ----
// one wave per node; lane owns features 2*lane, 2*lane+1 (HID=128)
__global__ __launch_bounds__(256)
void agg1_kernel(const u32* __restrict__ H32, const int* __restrict__ csr,
                 const int* __restrict__ row_start, const float* __restrict__ dinv,
                 const float* __restrict__ b1f, u32* __restrict__ H1, int N) {
    int wave = threadIdx.x >> 6, lane = threadIdx.x & 63;
    int n = blockIdx.x * 4 + wave;
    if (n >= N) return;
    int s0 = row_start[n], s1 = row_start[n + 1];
    float acc0 = 0.f, acc1 = 0.f;
    for (int base = s0; base < s1; base += 64) {
        int m = s1 - base; if (m > 64) m = 64;
        int myidx = (lane < m) ? csr[base + lane] : 0;
        int j = 0;
        for (; j + 4 <= m; j += 4) {
            int i0 = __shfl(myidx, j);
            int i1 = __shfl(myidx, j + 1);
            int i2 = __shfl(myidx, j + 2);
            int i3 = __shfl(myidx, j + 3);
            u32 h0 = H32[(size_t)i0 * 64 + lane];
            u32 h1 = H32[(size_t)i1 * 64 + lane];
            u32 h2 = H32[(size_t)i2 * 64 + lane];
            u32 h3 = H32[(size_t)i3 * 64 + lane];
            acc0 += bf2f(h0 & 0xffffu); acc1 += bf2f(h0 >> 16);
            acc0 += bf2f(h1 & 0xffffu); acc1 += bf2f(h1 >> 16);
            acc0 += bf2f(h2 & 0xffffu); acc1 += bf2f(h2 >> 16);
            acc0 += bf2f(h3 & 0xffffu); acc1 += bf2f(h3 >> 16);
        }
        for (; j < m; ++j) {
            int s = __shfl(myidx, j);
            u32 h = H32[(size_t)s * 64 + lane];
            acc0 += bf2f(h & 0xffffu); acc1 += bf2f(h >> 16);
        }
    }
    float wn = dinv[n];
    float v0 = fmaxf(wn * acc0 + b1f[2 * lane], 0.f);
    float v1 = fmaxf(wn * acc1 + b1f[2 * lane + 1], 0.f);
    H1[(size_t)n * 64 + lane] = (u32)f2bf(v0) | ((u32)f2bf(v1) << 16);
}

// ---- layer-2 aggregation + bias + log_softmax; H2 pre-scaled by dinv[src] ----
// one half-wave (32 lanes) per node; lane = class
__global__ __launch_bounds__(256)
void agg2_kernel(const u16* __restrict__ H2, const int* __restrict__ csr,
                 const int* __restrict__ row_start, const float* __restrict__ dinv,
                 const float* __restrict__ b2f, const int* __restrict__ ff,
                 void* __restrict__ out, int N) {
    int half = threadIdx.x >> 5;            // 0..7
    int c = threadIdx.x & 31;
    int n = blockIdx.x * 8 + half;
    if (n >= N) return;
    int s0 = row_start[n], s1 = row_start[n + 1];
    float acc = 0.f;
    for (int base = s0; base < s1; base += 32) {
        int m = s1 - base; if (m > 32) m = 32;
        int myidx = (c < m) ? csr[base + c] : 0;
        int j = 0;
        for (; j + 4 <= m; j += 4) {
            int i0 = __shfl(myidx, j, 32);
            int i1 = __shfl(myidx, j + 1, 32);
            int i2 = __shfl(myidx, j + 2, 32);
            int i3 = __shfl(myidx, j + 3, 32);
            float h0 = bf2f(H2[(size_t)i0 * 32 + c]);
            float h1 = bf2f(H2[(size_t)i1 * 32 + c]);
            float h2 = bf2f(H2[(size_t)i2 * 32 + c]);
            float h3 = bf2f(H2[(size_t)i3 * 32 + c]);
            acc += h0 + h1 + h2 + h3;
        }
        for (; j < m; ++j) {
            int s = __shfl(myidx, j, 32);
            acc += bf2f(H2[(size_t)s * 32 + c]);
        }
    }
    float tot = dinv[n] * acc + b2f[c];
    float mx = tot;
    #pragma unroll
    for (int m = 16; m; m >>= 1) mx = fmaxf(mx, __shfl_xor(mx, m, 32));
    float ex = expf(tot - mx);
    float sm = ex;
    #pragma unroll
    for (int m = 16; m; m >>= 1) sm += __shfl_xor(sm, m, 32);
    float r = tot - mx - logf(sm);
    if (*ff) ((float*)out)[(size_t)n * 32 + c] = r;
    else     ((u16*)out)[(size_t)n * 32 + c] = f2bf(r);
}

extern "C" void kernel_launch(void* const* d_in, const int* in_sizes, int n_in,
                              void* d_out, int out_size, void* d_ws, size_t ws_size,
                              hipStream_t stream) {
    const void* x  = d_in[0];
    const void* W1 = d_in[1];
    const void* b1 = d_in[2];
    const void* W2 = d_in[3];
    const void* b2 = d_in[4];
    const void* eb = d_in[5];

    const int HID  = in_sizes[2];            // 128
    const int CLS  = in_sizes[4];            // 32
    const int FEAT = in_sizes[1] / HID;      // 256
    const int N    = in_sizes[0] / FEAT;     // 100000
    const int E    = in_sizes[5] / 2;        // 1600000
    (void)n_in; (void)out_size;

    char* w = (char*)d_ws;
    size_t p = 0;
    auto alloc = [&](size_t bytes) {
        size_t o = p; p = (p + bytes + 255) & ~(size_t)255; return o;
    };
    int*   flags     = (int*)  (w + alloc(32));
    size_t deg_off   =          alloc((size_t)N * 4);
    int*   deg       = (int*)  (w + deg_off);
    size_t cur_off   =          alloc((size_t)N * 4);
    int*   cursor    = (int*)  (w + cur_off);
    int*   row_start = (int*)  (w + alloc((size_t)(N + 1) * 4));
    int*   bsums     = (int*)  (w + alloc(512 * 4));
    int*   srcA      = (int*)  (w + alloc((size_t)E * 4));
    int*   dstA      = (int*)  (w + alloc((size_t)E * 4));
    int*   csr       = (int*)  (w + alloc((size_t)E * 4));
    float* dinv      = (float*)(w + alloc((size_t)N * 4));
    float* b1f       = (float*)(w + alloc((size_t)HID * 4));
    float* b2f       = (float*)(w + alloc((size_t)CLS * 4));
    u16*   B1p       = (u16*)  (w + alloc((size_t)FEAT * HID * 2));
    u16*   B2p       = (u16*)  (w + alloc((size_t)HID * CLS * 2));
    u16*   H         = (u16*)  (w + alloc((size_t)N * HID * 2));
    u16*   H1        = (u16*)  (w + alloc((size_t)N * HID * 2));
    u16*   H2        = (u16*)  (w + alloc((size_t)N * CLS * 2));
    if (p > ws_size) return;   // workspace too small: fail visibly

    detect_kernel<<<1, 256, 0, stream>>>((const u32*)x, (const int*)eb, flags);

    // zero deg + cursor (contiguous region) BEFORE convert (which builds deg)
    size_t zlen = (cur_off - deg_off) + (size_t)N * 4;
    hipMemsetAsync(deg, 0, zlen, stream);

    convert_kernel<<<(2 * E + 255) / 256, 256, 0, stream>>>(eb, flags, srcA, dstA, deg, E);
    dinv_kernel<<<(N + 255) / 256, 256, 0, stream>>>(deg, dinv, N);
    bconv_kernel<<<1, 256, 0, stream>>>(b1, b2, flags, b1f, b2f, HID, CLS);

    int nb = (N + 255) / 256;
    scan_block_kernel<<<nb, 256, 0, stream>>>(deg, row_start, bsums, N);
    scan_sums_kernel<<<1, 512, 0, stream>>>(bsums, nb);
    scan_add_kernel<<<nb, 256, 0, stream>>>(row_start, bsums, N, E);

    fill_kernel<<<(E + 255) / 256, 256, 0, stream>>>(srcA, dstA, row_start, cursor, csr, E);

    prepack_kernel<8, 8, 128><<<(8 * 8 * 64 * 8 + 255) / 256, 256, 0, stream>>>(W1, flags, B1p);
    prepack_kernel<2, 4, 32><<<(2 * 4 * 64 * 8 + 255) / 256, 256, 0, stream>>>(W2, flags, B2p);

    int gblocks = (N + 63) / 64;
    gemm_kernel<8, 8><<<gblocks, 256, 0, stream>>>(x, flags, B1p, dinv, H, N);
    agg1_kernel<<<(N + 3) / 4, 256, 0, stream>>>((const u32*)H, csr, row_start, dinv, b1f,
                                                 (u32*)H1, N);
    gemm_kernel<2, 4><<<gblocks, 256, 0, stream>>>(H1, flags + 1, B2p, dinv, H2, N);
    agg2_kernel<<<(N + 3) / 4 * 2, 256, 0, stream>>>(H2, csr, row_start, dinv, b2f, flags,
                                                     (void*)d_out, N);
}

// Round 4
// 405.231 us; speedup vs baseline: 1.5642x; 1.1541x over previous
//
#include <hip/hip_runtime.h>

typedef unsigned short u16;
typedef unsigned int   u32;
typedef __attribute__((ext_vector_type(8))) short short8;
typedef __attribute__((ext_vector_type(4))) float f32x4;

constexpr int BSH = 9;               // bucket = dst >> 9  (512 dsts/bucket)
constexpr int BSZ = 1 << BSH;

__device__ inline float bf2f(u32 bits16) {
    union { u32 u; float f; } c; c.u = bits16 << 16; return c.f;
}
__device__ inline u16 f2bf(float f) {
    union { float f; u32 u; } c; c.f = f;
    u32 u = c.u;
    u32 r = (u + 0x7fffu + ((u >> 16) & 1u)) >> 16;
    return (u16)r;
}
__device__ inline int ld_edge(const void* eb, int f64, size_t idx) {
    return f64 ? (int)((const long long*)eb)[idx] : ((const int*)eb)[idx];
}

// ---------------- runtime dtype detection ----------------
// flags[0]: 1 => float inputs are fp32, 0 => bf16
// flags[1]: constant 0 — "ff" for internal bf16 GEMM inputs
// flags[2]: 1 => edge_index is int64, 0 => int32
__global__ void detect_kernel(const u32* xw, const int* ebuf_int, int* flags) {
    __shared__ int cnt;
    if (threadIdx.x == 0) cnt = 0;
    __syncthreads();
    u32 w = xw[threadIdx.x];
    int e = (int)((w >> 7) & 0xffu);   // bf16-pair: exponent of low element
    if (e >= 110 && e <= 145) atomicAdd(&cnt, 1);
    int ev = ebuf_int[2 * threadIdx.x + 1];
    unsigned long long any = __ballot(ev != 0);
    __syncthreads();
    if (threadIdx.x == 0) {
        flags[0] = (cnt < 192) ? 1 : 0;
        flags[1] = 0;
        flags[2] = (any == 0ULL) ? 1 : 0;
    }
}

// ---------------- bias convert to fp32 ----------------
__global__ void bconv_kernel(const void* b1, const void* b2, const int* flags,
                             float* b1f, float* b2f, int HID, int CLS) {
    int i = blockIdx.x * 256 + threadIdx.x;
    int f = flags[0];
    if (i < HID) b1f[i] = f ? ((const float*)b1)[i] : bf2f(((const u16*)b1)[i]);
    if (i < CLS) b2f[i] = f ? ((const float*)b2)[i] : bf2f(((const u16*)b2)[i]);
}

// ---------------- bucket histogram over dst (EPT=16) ----------------
__global__ void hist_kernel(const void* eb, const int* flags, int* bucket_cnt,
                            int E, int nb) {
    __shared__ int hist[256];
    hist[threadIdx.x] = 0;
    __syncthreads();
    int f64 = flags[2];
    int base = blockIdx.x * 4096;
    #pragma unroll
    for (int k = 0; k < 16; ++k) {
        int e = base + k * 256 + threadIdx.x;
        if (e < E) {
            int d = ld_edge(eb, f64, (size_t)E + e);
            atomicAdd(&hist[d >> BSH], 1);
        }
    }
    __syncthreads();
    int b = threadIdx.x;
    if (b < nb) { int c = hist[b]; if (c) atomicAdd(&bucket_cnt[b], c); }
}

// ---------------- bucket exclusive scan (nb <= 256) + cursor init ----------------
__global__ void bucket_scan_kernel(const int* bucket_cnt, int* bucket_base,
                                   int* bucket_rsv, int nb, int E) {
    __shared__ int wsum[4];
    int t = threadIdx.x, lane = t & 63, wv = t >> 6;
    int v = (t < nb) ? bucket_cnt[t] : 0;
    int inc = v;
    #pragma unroll
    for (int d = 1; d < 64; d <<= 1) {
        int tmp = __shfl_up(inc, d, 64);
        if (lane >= d) inc += tmp;
    }
    if (lane == 63) wsum[wv] = inc;
    __syncthreads();
    int off = 0;
    #pragma unroll
    for (int w = 0; w < 4; ++w) if (w < wv) off += wsum[w];
    int excl = off + inc - v;
    if (t <= nb) bucket_base[t] = (t == nb) ? E : excl;
    if (t < nb) bucket_rsv[t] = excl;
}

// ---------------- passA: scatter edges into dst-buckets (EPT=32) ----------------
__global__ __launch_bounds__(256)
void passA_kernel(const void* eb, const int* flags, int* bucket_rsv,
                  int* bsrc, int* bdst, int E, int nb) {
    __shared__ int hist[256];
    __shared__ int rbase[256];
    hist[threadIdx.x] = 0;
    __syncthreads();
    int f64 = flags[2];
    int base = blockIdx.x * 8192;
    #pragma unroll
    for (int k = 0; k < 32; ++k) {
        int e = base + k * 256 + threadIdx.x;
        if (e < E) {
            int d = ld_edge(eb, f64, (size_t)E + e);
            atomicAdd(&hist[d >> BSH], 1);
        }
    }
    __syncthreads();
    {
        int b = threadIdx.x;
        int c = (b < nb) ? hist[b] : 0;
        rbase[b] = c ? atomicAdd(&bucket_rsv[b], c) : 0;
        hist[b] = 0;
    }
    __syncthreads();
    #pragma unroll
    for (int k = 0; k < 32; ++k) {
        int e = base + k * 256 + threadIdx.x;
        if (e < E) {
            int d = ld_edge(eb, f64, (size_t)E + e);
            int s = ld_edge(eb, f64, (size_t)e);
            int bb = d >> BSH;
            int r = atomicAdd(&hist[bb], 1);
            int pos = rbase[bb] + r;
            bsrc[pos] = s;
            bdst[pos] = d;
        }
    }
}

// ------- degB: per-bucket degree count (LDS) -> deg + dinv, coalesced -------
__global__ __launch_bounds__(256)
void degB_kernel(const int* bdst, const int* bucket_base, int* deg, float* dinv, int N) {
    __shared__ int cur[BSZ];
    int b = blockIdx.x, d0 = b << BSH;
    for (int i = threadIdx.x; i < BSZ; i += 256) cur[i] = 0;
    __syncthreads();
    int e0 = bucket_base[b], e1 = bucket_base[b + 1];
    for (int e = e0 + threadIdx.x; e < e1; e += 256)
        atomicAdd(&cur[bdst[e] - d0], 1);
    __syncthreads();
    for (int i = threadIdx.x; i < BSZ; i += 256) {
        int d = d0 + i;
        if (d < N) {
            int c = cur[i];
            deg[d] = c;
            dinv[d] = (c > 0) ? 1.0f / sqrtf((float)c) : 0.0f;
        }
    }
}

// ---------------- passB: bucket -> csr (LDS cursor, local writes) ----------------
__global__ __launch_bounds__(256)
void passB_kernel(const int* bsrc, const int* bdst, const int* bucket_base,
                  const int* row_start, int* csr) {
    __shared__ int cur[BSZ];
    int b = blockIdx.x, d0 = b << BSH;
    for (int i = threadIdx.x; i < BSZ; i += 256) cur[i] = 0;
    __syncthreads();
    int e0 = bucket_base[b], e1 = bucket_base[b + 1];
    for (int e = e0 + threadIdx.x; e < e1; e += 256) {
        int d = bdst[e];
        int s = bsrc[e];
        int r = atomicAdd(&cur[d - d0], 1);
        csr[row_start[d] + r] = s;
    }
}

// ---------------- exclusive scan over deg (3 kernels) ----------------
__device__ inline int wave_incl_scan(int v, int lane) {
    #pragma unroll
    for (int d = 1; d < 64; d <<= 1) {
        int t = __shfl_up(v, d, 64);
        if (lane >= d) v += t;
    }
    return v;
}

__global__ void scan_block_kernel(const int* deg, int* row_start, int* bsums, int N) {
    __shared__ int wsum[4];
    int t = threadIdx.x, lane = t & 63, wv = t >> 6;
    int i = blockIdx.x * 256 + t;
    int v = (i < N) ? deg[i] : 0;
    int inc = wave_incl_scan(v, lane);
    if (lane == 63) wsum[wv] = inc;
    __syncthreads();
    int off = 0;
    #pragma unroll
    for (int w = 0; w < 4; ++w) if (w < wv) off += wsum[w];
    if (i < N) row_start[i] = off + inc - v;
    if (t == 255) bsums[blockIdx.x] = off + inc;
}

__global__ void scan_sums_kernel(int* bsums, int nb) {
    __shared__ int wsum[8];
    int t = threadIdx.x, lane = t & 63, wv = t >> 6;
    int v = (t < nb) ? bsums[t] : 0;
    int inc = wave_incl_scan(v, lane);
    if (lane == 63) wsum[wv] = inc;
    __syncthreads();
    int off = 0;
    #pragma unroll
    for (int w = 0; w < 8; ++w) if (w < wv) off += wsum[w];
    if (t < nb) bsums[t] = off + inc - v;   // exclusive
}

__global__ void scan_add_kernel(int* row_start, const int* bsums, int N, int E) {
    int i = blockIdx.x * 256 + threadIdx.x;
    if (i < N) row_start[i] += bsums[blockIdx.x];
    if (blockIdx.x == 0 && threadIdx.x == 0) row_start[N] = E;
}

// ---------------- weight prepack into MFMA B-fragment layout ----------------
template<int NT, int KT, int NCOLS>
__global__ void prepack_kernel(const void* W, const int* flags, u16* pack) {
    int p = blockIdx.x * 256 + threadIdx.x;
    constexpr int TOT = NT * KT * 64 * 8;
    if (p >= TOT) return;
    int j = p & 7, lane = (p >> 3) & 63, fk = p >> 9;
    int kk = fk % KT, nt = fk / KT;
    int n = nt * 16 + (lane & 15);
    int k = kk * 32 + (lane >> 4) * 8 + j;
    u16 v = flags[0] ? f2bf(((const float*)W)[k * NCOLS + n])
                     : ((const u16*)W)[k * NCOLS + n];
    pack[p] = v;
}

// ---- GEMM: A[M,K] (fp32/bf16 per *ff) x Bpack -> C bf16, rows scaled by dinv ----
template<int NT, int KT>
__global__ __launch_bounds__(256)
void gemm_kernel(const void* __restrict__ A, const int* __restrict__ ff,
                 const u16* __restrict__ Bpack, const float* __restrict__ dinv,
                 u16* __restrict__ C, int M) {
    constexpr int K = KT * 32;
    constexpr int Ncols = NT * 16;
    __shared__ short8 lds[NT * KT * 64];
    for (int i = threadIdx.x; i < NT * KT * 64; i += 256)
        lds[i] = ((const short8*)Bpack)[i];
    bool fA = (*ff != 0);
    __syncthreads();
    int wave = threadIdx.x >> 6, lane = threadIdx.x & 63;
    int m0 = (blockIdx.x * 4 + wave) * 16;
    if (m0 >= M) return;
    int q = lane >> 4;
    int row = m0 + (lane & 15);
    f32x4 acc[NT];
    #pragma unroll
    for (int nt = 0; nt < NT; ++nt) acc[nt] = (f32x4){0.f, 0.f, 0.f, 0.f};
    #pragma unroll
    for (int kk = 0; kk < KT; ++kk) {
        short8 a;
        if (fA) {
            const float* Af = (const float*)A + (size_t)row * K + kk * 32 + q * 8;
            f32x4 v0 = ((const f32x4*)Af)[0];
            f32x4 v1 = ((const f32x4*)Af)[1];
            union { short8 s; u16 u[8]; } pa;
            pa.u[0] = f2bf(v0[0]); pa.u[1] = f2bf(v0[1]);
            pa.u[2] = f2bf(v0[2]); pa.u[3] = f2bf(v0[3]);
            pa.u[4] = f2bf(v1[0]); pa.u[5] = f2bf(v1[1]);
            pa.u[6] = f2bf(v1[2]); pa.u[7] = f2bf(v1[3]);
            a = pa.s;
        } else {
            a = ((const short8*)((const u16*)A + (size_t)row * K))[kk * 4 + q];
        }
        #pragma unroll
        for (int nt = 0; nt < NT; ++nt) {
            short8 b = lds[(nt * KT + kk) * 64 + lane];
            acc[nt] = __builtin_amdgcn_mfma_f32_16x16x32_bf16(a, b, acc[nt], 0, 0, 0);
        }
    }
    float sc[4];
    #pragma unroll
    for (int r = 0; r < 4; ++r) sc[r] = dinv[m0 + q * 4 + r];
    #pragma unroll
    for (int nt = 0; nt < NT; ++nt) {
        int col = nt * 16 + (lane & 15);
        #pragma unroll
        for (int r = 0; r < 4; ++r) {
            int rrow = m0 + q * 4 + r;
            C[(size_t)rrow * Ncols + col] = f2bf(acc[nt][r] * sc[r]);
        }
    }
}

// ---- layer-1 aggregation: H rows pre-scaled by dinv[src]; +bias, relu ----
__global__ __launch_bounds__(256)
void agg1_kernel(const u32* __restrict__ H32, const int* __restrict__ csr,
                 const int* __restrict__ row_start, const float* __restrict__ dinv,
                 const float* __restrict__ b1f, u32* __restrict__ H1, int N) {
    int wave = threadIdx.x >> 6, lane = threadIdx.x & 63;
    int n = blockIdx.x * 4 + wave;
    if (n >= N) return;
    int s0 = row_start[n], s1 = row_start[n + 1];
    float acc0 = 0.f, acc1 = 0.f;
    for (int base = s0; base < s1; base += 64) {
        int m = s1 - base; if (m > 64) m = 64;
        int myidx = (lane < m) ? csr[base + lane] : 0;
        int j = 0;
        for (; j + 4 <= m; j += 4) {
            int i0 = __shfl(myidx, j);
            int i1 = __shfl(myidx, j + 1);
            int i2 = __shfl(myidx, j + 2);
            int i3 = __shfl(myidx, j + 3);
            u32 h0 = H32[(size_t)i0 * 64 + lane];
            u32 h1 = H32[(size_t)i1 * 64 + lane];
            u32 h2 = H32[(size_t)i2 * 64 + lane];
            u32 h3 = H32[(size_t)i3 * 64 + lane];
            acc0 += bf2f(h0 & 0xffffu); acc1 += bf2f(h0 >> 16);
            acc0 += bf2f(h1 & 0xffffu); acc1 += bf2f(h1 >> 16);
            acc0 += bf2f(h2 & 0xffffu); acc1 += bf2f(h2 >> 16);
            acc0 += bf2f(h3 & 0xffffu); acc1 += bf2f(h3 >> 16);
        }
        for (; j < m; ++j) {
            int s = __shfl(myidx, j);
            u32 h = H32[(size_t)s * 64 + lane];
            acc0 += bf2f(h & 0xffffu); acc1 += bf2f(h >> 16);
        }
    }
    float wn = dinv[n];
    float v0 = fmaxf(wn * acc0 + b1f[2 * lane], 0.f);
    float v1 = fmaxf(wn * acc1 + b1f[2 * lane + 1], 0.f);
    H1[(size_t)n * 64 + lane] = (u32)f2bf(v0) | ((u32)f2bf(v1) << 16);
}

// ---- layer-2 aggregation + bias + log_softmax; H2 pre-scaled by dinv[src] ----
__global__ __launch_bounds__(256)
void agg2_kernel(const u16* __restrict__ H2, const int* __restrict__ csr,
                 const int* __restrict__ row_start, const float* __restrict__ dinv,
                 const float* __restrict__ b2f, const int* __restrict__ ff,
                 void* __restrict__ out, int N) {
    int half = threadIdx.x >> 5;            // 0..7
    int c = threadIdx.x & 31;
    int n = blockIdx.x * 8 + half;
    if (n >= N) return;
    int s0 = row_start[n], s1 = row_start[n + 1];
    float acc = 0.f;
    for (int base = s0; base < s1; base += 32) {
        int m = s1 - base; if (m > 32) m = 32;
        int myidx = (c < m) ? csr[base + c] : 0;
        int j = 0;
        for (; j + 4 <= m; j += 4) {
            int i0 = __shfl(myidx, j, 32);
            int i1 = __shfl(myidx, j + 1, 32);
            int i2 = __shfl(myidx, j + 2, 32);
            int i3 = __shfl(myidx, j + 3, 32);
            float h0 = bf2f(H2[(size_t)i0 * 32 + c]);
            float h1 = bf2f(H2[(size_t)i1 * 32 + c]);
            float h2 = bf2f(H2[(size_t)i2 * 32 + c]);
            float h3 = bf2f(H2[(size_t)i3 * 32 + c]);
            acc += h0 + h1 + h2 + h3;
        }
        for (; j < m; ++j) {
            int s = __shfl(myidx, j, 32);
            acc += bf2f(H2[(size_t)s * 32 + c]);
        }
    }
    float tot = dinv[n] * acc + b2f[c];
    float mx = tot;
    #pragma unroll
    for (int m = 16; m; m >>= 1) mx = fmaxf(mx, __shfl_xor(mx, m, 32));
    float ex = expf(tot - mx);
    float sm = ex;
    #pragma unroll
    for (int m = 16; m; m >>= 1) sm += __shfl_xor(sm, m, 32);
    float r = tot - mx - logf(sm);
    if (*ff) ((float*)out)[(size_t)n * 32 + c] = r;
    else     ((u16*)out)[(size_t)n * 32 + c] = f2bf(r);
}

extern "C" void kernel_launch(void* const* d_in, const int* in_sizes, int n_in,
                              void* d_out, int out_size, void* d_ws, size_t ws_size,
                              hipStream_t stream) {
    const void* x  = d_in[0];
    const void* W1 = d_in[1];
    const void* b1 = d_in[2];
    const void* W2 = d_in[3];
    const void* b2 = d_in[4];
    const void* eb = d_in[5];

    const int HID  = in_sizes[2];            // 128
    const int CLS  = in_sizes[4];            // 32
    const int FEAT = in_sizes[1] / HID;      // 256
    const int N    = in_sizes[0] / FEAT;     // 100000
    const int E    = in_sizes[5] / 2;        // 1600000
    const int nb   = (N + BSZ - 1) >> BSH;   // 196 (assumes <= 256)
    (void)n_in; (void)out_size;

    char* w = (char*)d_ws;
    size_t p = 0;
    auto alloc = [&](size_t bytes) {
        size_t o = p; p = (p + bytes + 255) & ~(size_t)255; return o;
    };
    int*   flags      = (int*)  (w + alloc(32));
    int*   deg        = (int*)  (w + alloc((size_t)N * 4));
    int*   row_start  = (int*)  (w + alloc((size_t)(N + 1) * 4));
    int*   bsums      = (int*)  (w + alloc(512 * 4));
    int*   bucket_cnt = (int*)  (w + alloc(257 * 4));
    int*   bucket_base= (int*)  (w + alloc(257 * 4));
    int*   bucket_rsv = (int*)  (w + alloc(256 * 4));
    int*   bsrc       = (int*)  (w + alloc((size_t)E * 4));
    int*   bdst       = (int*)  (w + alloc((size_t)E * 4));
    int*   csr        = (int*)  (w + alloc((size_t)E * 4));
    float* dinv       = (float*)(w + alloc((size_t)N * 4));
    float* b1f        = (float*)(w + alloc((size_t)HID * 4));
    float* b2f        = (float*)(w + alloc((size_t)CLS * 4));
    u16*   B1p        = (u16*)  (w + alloc((size_t)FEAT * HID * 2));
    u16*   B2p        = (u16*)  (w + alloc((size_t)HID * CLS * 2));
    u16*   H          = (u16*)  (w + alloc((size_t)N * HID * 2));
    u16*   H1         = (u16*)  (w + alloc((size_t)N * HID * 2));
    u16*   H2         = (u16*)  (w + alloc((size_t)N * CLS * 2));
    if (p > ws_size) return;   // workspace too small: fail visibly

    detect_kernel<<<1, 256, 0, stream>>>((const u32*)x, (const int*)eb, flags);
    hipMemsetAsync(bucket_cnt, 0, 257 * 4, stream);
    bconv_kernel<<<1, 256, 0, stream>>>(b1, b2, flags, b1f, b2f, HID, CLS);

    hist_kernel<<<(E + 4095) / 4096, 256, 0, stream>>>(eb, flags, bucket_cnt, E, nb);
    bucket_scan_kernel<<<1, 256, 0, stream>>>(bucket_cnt, bucket_base, bucket_rsv, nb, E);
    passA_kernel<<<(E + 8191) / 8192, 256, 0, stream>>>(eb, flags, bucket_rsv,
                                                        bsrc, bdst, E, nb);
    degB_kernel<<<nb, 256, 0, stream>>>(bdst, bucket_base, deg, dinv, N);

    int nsb = (N + 255) / 256;
    scan_block_kernel<<<nsb, 256, 0, stream>>>(deg, row_start, bsums, N);
    scan_sums_kernel<<<1, 512, 0, stream>>>(bsums, nsb);
    scan_add_kernel<<<nsb, 256, 0, stream>>>(row_start, bsums, N, E);

    passB_kernel<<<nb, 256, 0, stream>>>(bsrc, bdst, bucket_base, row_start, csr);

    prepack_kernel<8, 8, 128><<<(8 * 8 * 64 * 8 + 255) / 256, 256, 0, stream>>>(W1, flags, B1p);
    prepack_kernel<2, 4, 32><<<(2 * 4 * 64 * 8 + 255) / 256, 256, 0, stream>>>(W2, flags, B2p);

    int gblocks = (N + 63) / 64;
    gemm_kernel<8, 8><<<gblocks, 256, 0, stream>>>(x, flags, B1p, dinv, H, N);
    agg1_kernel<<<(N + 3) / 4, 256, 0, stream>>>((const u32*)H, csr, row_start, dinv, b1f,
                                                 (u32*)H1, N);
    gemm_kernel<2, 4><<<gblocks, 256, 0, stream>>>(H1, flags + 1, B2p, dinv, H2, N);
    agg2_kernel<<<(N + 7) / 8, 256, 0, stream>>>(H2, csr, row_start, dinv, b2f, flags,
                                                 (void*)d_out, N);
}

// Round 5
// 401.225 us; speedup vs baseline: 1.5799x; 1.0100x over previous
//
#include <hip/hip_runtime.h>

typedef unsigned short u16;
typedef unsigned int   u32;
typedef __attribute__((ext_vector_type(8))) short short8;
typedef __attribute__((ext_vector_type(4))) float f32x4;

constexpr int BSH = 9;               // bucket = dst >> 9  (512 dsts/bucket)
constexpr int BSZ = 1 << BSH;

__device__ inline float bf2f(u32 bits16) {
    union { u32 u; float f; } c; c.u = bits16 << 16; return c.f;
}
// round-half-up bf16 (cheap: add + shift); |err| <= 0.5 ulp like RNE
__device__ inline u16 f2bf(float f) {
    union { float f; u32 u; } c; c.f = f;
    return (u16)((c.u + 0x8000u) >> 16);
}
__device__ inline int ld_edge(const void* eb, int f64, size_t idx) {
    return f64 ? (int)((const long long*)eb)[idx] : ((const int*)eb)[idx];
}

// ---------------- runtime dtype detection ----------------
// flags[0]: 1 => float inputs are fp32, 0 => bf16
// flags[1]: constant 0 — "ff" for internal bf16 GEMM inputs
// flags[2]: 1 => edge_index is int64, 0 => int32
__global__ void detect_kernel(const u32* xw, const int* ebuf_int, int* flags) {
    __shared__ int cnt;
    if (threadIdx.x == 0) cnt = 0;
    __syncthreads();
    u32 w = xw[threadIdx.x];
    int e = (int)((w >> 7) & 0xffu);   // bf16-pair: exponent of low element
    if (e >= 110 && e <= 145) atomicAdd(&cnt, 1);
    int ev = ebuf_int[2 * threadIdx.x + 1];
    unsigned long long any = __ballot(ev != 0);
    __syncthreads();
    if (threadIdx.x == 0) {
        flags[0] = (cnt < 192) ? 1 : 0;
        flags[1] = 0;
        flags[2] = (any == 0ULL) ? 1 : 0;
    }
}

// ---------------- bias convert to fp32 ----------------
__global__ void bconv_kernel(const void* b1, const void* b2, const int* flags,
                             float* b1f, float* b2f, int HID, int CLS) {
    int i = blockIdx.x * 256 + threadIdx.x;
    int f = flags[0];
    if (i < HID) b1f[i] = f ? ((const float*)b1)[i] : bf2f(((const u16*)b1)[i]);
    if (i < CLS) b2f[i] = f ? ((const float*)b2)[i] : bf2f(((const u16*)b2)[i]);
}

// ---------------- bucket histogram over dst (EPT=16) ----------------
__global__ void hist_kernel(const void* eb, const int* flags, int* bucket_cnt,
                            int E, int nb) {
    __shared__ int hist[256];
    hist[threadIdx.x] = 0;
    __syncthreads();
    int f64 = flags[2];
    int base = blockIdx.x * 4096;
    #pragma unroll
    for (int k = 0; k < 16; ++k) {
        int e = base + k * 256 + threadIdx.x;
        if (e < E) {
            int d = ld_edge(eb, f64, (size_t)E + e);
            atomicAdd(&hist[d >> BSH], 1);
        }
    }
    __syncthreads();
    int b = threadIdx.x;
    if (b < nb) { int c = hist[b]; if (c) atomicAdd(&bucket_cnt[b], c); }
}

// ---------------- bucket exclusive scan (nb <= 256) + cursor init ----------------
__global__ void bucket_scan_kernel(const int* bucket_cnt, int* bucket_base,
                                   int* bucket_rsv, int nb, int E) {
    __shared__ int wsum[4];
    int t = threadIdx.x, lane = t & 63, wv = t >> 6;
    int v = (t < nb) ? bucket_cnt[t] : 0;
    int inc = v;
    #pragma unroll
    for (int d = 1; d < 64; d <<= 1) {
        int tmp = __shfl_up(inc, d, 64);
        if (lane >= d) inc += tmp;
    }
    if (lane == 63) wsum[wv] = inc;
    __syncthreads();
    int off = 0;
    #pragma unroll
    for (int w = 0; w < 4; ++w) if (w < wv) off += wsum[w];
    int excl = off + inc - v;
    if (t <= nb) bucket_base[t] = (t == nb) ? E : excl;
    if (t < nb) bucket_rsv[t] = excl;
}

// ---------------- passA: scatter edges into dst-buckets (EPT=32) ----------------
__global__ __launch_bounds__(256)
void passA_kernel(const void* eb, const int* flags, int* bucket_rsv,
                  int* bsrc, int* bdst, int E, int nb) {
    __shared__ int hist[256];
    __shared__ int rbase[256];
    hist[threadIdx.x] = 0;
    __syncthreads();
    int f64 = flags[2];
    int base = blockIdx.x * 8192;
    #pragma unroll
    for (int k = 0; k < 32; ++k) {
        int e = base + k * 256 + threadIdx.x;
        if (e < E) {
            int d = ld_edge(eb, f64, (size_t)E + e);
            atomicAdd(&hist[d >> BSH], 1);
        }
    }
    __syncthreads();
    {
        int b = threadIdx.x;
        int c = (b < nb) ? hist[b] : 0;
        rbase[b] = c ? atomicAdd(&bucket_rsv[b], c) : 0;
        hist[b] = 0;
    }
    __syncthreads();
    #pragma unroll
    for (int k = 0; k < 32; ++k) {
        int e = base + k * 256 + threadIdx.x;
        if (e < E) {
            int d = ld_edge(eb, f64, (size_t)E + e);
            int s = ld_edge(eb, f64, (size_t)e);
            int bb = d >> BSH;
            int r = atomicAdd(&hist[bb], 1);
            int pos = rbase[bb] + r;
            bsrc[pos] = s;
            bdst[pos] = d;
        }
    }
}

// ------- degB: per-bucket degree count (LDS) -> deg + dinv, coalesced -------
__global__ __launch_bounds__(256)
void degB_kernel(const int* bdst, const int* bucket_base, int* deg, float* dinv, int N) {
    __shared__ int cur[BSZ];
    int b = blockIdx.x, d0 = b << BSH;
    for (int i = threadIdx.x; i < BSZ; i += 256) cur[i] = 0;
    __syncthreads();
    int e0 = bucket_base[b], e1 = bucket_base[b + 1];
    for (int e = e0 + threadIdx.x; e < e1; e += 256)
        atomicAdd(&cur[bdst[e] - d0], 1);
    __syncthreads();
    for (int i = threadIdx.x; i < BSZ; i += 256) {
        int d = d0 + i;
        if (d < N) {
            int c = cur[i];
            deg[d] = c;
            dinv[d] = (c > 0) ? 1.0f / sqrtf((float)c) : 0.0f;
        }
    }
}

// ---------------- passB: bucket -> csr (LDS cursor, local writes) ----------------
__global__ __launch_bounds__(256)
void passB_kernel(const int* bsrc, const int* bdst, const int* bucket_base,
                  const int* row_start, int* csr) {
    __shared__ int cur[BSZ];
    int b = blockIdx.x, d0 = b << BSH;
    for (int i = threadIdx.x; i < BSZ; i += 256) cur[i] = 0;
    __syncthreads();
    int e0 = bucket_base[b], e1 = bucket_base[b + 1];
    for (int e = e0 + threadIdx.x; e < e1; e += 256) {
        int d = bdst[e];
        int s = bsrc[e];
        int r = atomicAdd(&cur[d - d0], 1);
        csr[row_start[d] + r] = s;
    }
}

// ---------------- exclusive scan over deg (3 kernels) ----------------
__device__ inline int wave_incl_scan(int v, int lane) {
    #pragma unroll
    for (int d = 1; d < 64; d <<= 1) {
        int t = __shfl_up(v, d, 64);
        if (lane >= d) v += t;
    }
    return v;
}

__global__ void scan_block_kernel(const int* deg, int* row_start, int* bsums, int N) {
    __shared__ int wsum[4];
    int t = threadIdx.x, lane = t & 63, wv = t >> 6;
    int i = blockIdx.x * 256 + t;
    int v = (i < N) ? deg[i] : 0;
    int inc = wave_incl_scan(v, lane);
    if (lane == 63) wsum[wv] = inc;
    __syncthreads();
    int off = 0;
    #pragma unroll
    for (int w = 0; w < 4; ++w) if (w < wv) off += wsum[w];
    if (i < N) row_start[i] = off + inc - v;
    if (t == 255) bsums[blockIdx.x] = off + inc;
}

__global__ void scan_sums_kernel(int* bsums, int nb) {
    __shared__ int wsum[8];
    int t = threadIdx.x, lane = t & 63, wv = t >> 6;
    int v = (t < nb) ? bsums[t] : 0;
    int inc = wave_incl_scan(v, lane);
    if (lane == 63) wsum[wv] = inc;
    __syncthreads();
    int off = 0;
    #pragma unroll
    for (int w = 0; w < 8; ++w) if (w < wv) off += wsum[w];
    if (t < nb) bsums[t] = off + inc - v;   // exclusive
}

__global__ void scan_add_kernel(int* row_start, const int* bsums, int N, int E) {
    int i = blockIdx.x * 256 + threadIdx.x;
    if (i < N) row_start[i] += bsums[blockIdx.x];
    if (blockIdx.x == 0 && threadIdx.x == 0) row_start[N] = E;
}

// ---------------- weight prepack into MFMA B-fragment layout ----------------
template<int NT, int KT, int NCOLS>
__global__ void prepack_kernel(const void* W, const int* flags, u16* pack) {
    int p = blockIdx.x * 256 + threadIdx.x;
    constexpr int TOT = NT * KT * 64 * 8;
    if (p >= TOT) return;
    int j = p & 7, lane = (p >> 3) & 63, fk = p >> 9;
    int kk = fk % KT, nt = fk / KT;
    int n = nt * 16 + (lane & 15);
    int k = kk * 32 + (lane >> 4) * 8 + j;
    u16 v = flags[0] ? f2bf(((const float*)W)[k * NCOLS + n])
                     : ((const u16*)W)[k * NCOLS + n];
    pack[p] = v;
}

// ---- GEMM: A[M,K] (fp32/bf16 per *ff) x Bpack -> C bf16, rows scaled by dinv ----
// G row-groups of 16 per wave => 16*G rows/wave, 64*G rows/block (4 waves)
template<int NT, int KT, int G>
__global__ __launch_bounds__(256)
void gemm_kernel(const void* __restrict__ A, const int* __restrict__ ff,
                 const u16* __restrict__ Bpack, const float* __restrict__ dinv,
                 u16* __restrict__ C, int M) {
    constexpr int K = KT * 32;
    constexpr int Ncols = NT * 16;
    __shared__ short8 lds[NT * KT * 64];
    for (int i = threadIdx.x; i < NT * KT * 64; i += 256)
        lds[i] = ((const short8*)Bpack)[i];
    bool fA = (*ff != 0);
    __syncthreads();
    int wave = threadIdx.x >> 6, lane = threadIdx.x & 63;
    int m0 = (blockIdx.x * 4 + wave) * (16 * G);
    if (m0 >= M) return;
    int q = lane >> 4;
    int rowc[G];
    #pragma unroll
    for (int g = 0; g < G; ++g) {
        int r = m0 + g * 16 + (lane & 15);
        rowc[g] = (r < M) ? r : (M - 1);        // clamp for safe loads
    }
    f32x4 acc[G][NT];
    #pragma unroll
    for (int g = 0; g < G; ++g)
        #pragma unroll
        for (int nt = 0; nt < NT; ++nt) acc[g][nt] = (f32x4){0.f, 0.f, 0.f, 0.f};
    #pragma unroll
    for (int kk = 0; kk < KT; ++kk) {
        short8 a[G];
        #pragma unroll
        for (int g = 0; g < G; ++g) {
            if (fA) {
                const float* Af = (const float*)A + (size_t)rowc[g] * K + kk * 32 + q * 8;
                f32x4 v0 = ((const f32x4*)Af)[0];
                f32x4 v1 = ((const f32x4*)Af)[1];
                union { short8 s; u16 u[8]; } pa;
                pa.u[0] = f2bf(v0[0]); pa.u[1] = f2bf(v0[1]);
                pa.u[2] = f2bf(v0[2]); pa.u[3] = f2bf(v0[3]);
                pa.u[4] = f2bf(v1[0]); pa.u[5] = f2bf(v1[1]);
                pa.u[6] = f2bf(v1[2]); pa.u[7] = f2bf(v1[3]);
                a[g] = pa.s;
            } else {
                a[g] = ((const short8*)((const u16*)A + (size_t)rowc[g] * K))[kk * 4 + q];
            }
        }
        #pragma unroll
        for (int nt = 0; nt < NT; ++nt) {
            short8 b = lds[(nt * KT + kk) * 64 + lane];
            #pragma unroll
            for (int g = 0; g < G; ++g)
                acc[g][nt] = __builtin_amdgcn_mfma_f32_16x16x32_bf16(a[g], b, acc[g][nt], 0, 0, 0);
        }
    }
    #pragma unroll
    for (int g = 0; g < G; ++g) {
        float sc[4];
        #pragma unroll
        for (int r = 0; r < 4; ++r) {
            int rr = m0 + g * 16 + q * 4 + r;
            sc[r] = dinv[(rr < M) ? rr : (M - 1)];
        }
        #pragma unroll
        for (int nt = 0; nt < NT; ++nt) {
            int col = nt * 16 + (lane & 15);
            #pragma unroll
            for (int r = 0; r < 4; ++r) {
                int rrow = m0 + g * 16 + q * 4 + r;
                if (rrow < M)
                    C[(size_t)rrow * Ncols + col] = f2bf(acc[g][nt][r] * sc[r]);
            }
        }
    }
}

// ---- layer-1 aggregation: H rows pre-scaled by dinv[src]; +bias, relu ----
__global__ __launch_bounds__(256)
void agg1_kernel(const u32* __restrict__ H32, const int* __restrict__ csr,
                 const int* __restrict__ row_start, const float* __restrict__ dinv,
                 const float* __restrict__ b1f, u32* __restrict__ H1, int N) {
    int wave = threadIdx.x >> 6, lane = threadIdx.x & 63;
    int n = blockIdx.x * 4 + wave;
    if (n >= N) return;
    int s0 = row_start[n], s1 = row_start[n + 1];
    float acc0 = 0.f, acc1 = 0.f;
    for (int base = s0; base < s1; base += 64) {
        int m = s1 - base; if (m > 64) m = 64;
        int myidx = (lane < m) ? csr[base + lane] : 0;
        int j = 0;
        for (; j + 4 <= m; j += 4) {
            int i0 = __shfl(myidx, j);
            int i1 = __shfl(myidx, j + 1);
            int i2 = __shfl(myidx, j + 2);
            int i3 = __shfl(myidx, j + 3);
            u32 h0 = H32[(size_t)i0 * 64 + lane];
            u32 h1 = H32[(size_t)i1 * 64 + lane];
            u32 h2 = H32[(size_t)i2 * 64 + lane];
            u32 h3 = H32[(size_t)i3 * 64 + lane];
            acc0 += bf2f(h0 & 0xffffu); acc1 += bf2f(h0 >> 16);
            acc0 += bf2f(h1 & 0xffffu); acc1 += bf2f(h1 >> 16);
            acc0 += bf2f(h2 & 0xffffu); acc1 += bf2f(h2 >> 16);
            acc0 += bf2f(h3 & 0xffffu); acc1 += bf2f(h3 >> 16);
        }
        for (; j < m; ++j) {
            int s = __shfl(myidx, j);
            u32 h = H32[(size_t)s * 64 + lane];
            acc0 += bf2f(h & 0xffffu); acc1 += bf2f(h >> 16);
        }
    }
    float wn = dinv[n];
    float v0 = fmaxf(wn * acc0 + b1f[2 * lane], 0.f);
    float v1 = fmaxf(wn * acc1 + b1f[2 * lane + 1], 0.f);
    H1[(size_t)n * 64 + lane] = (u32)f2bf(v0) | ((u32)f2bf(v1) << 16);
}

// ---- layer-2 aggregation + bias + log_softmax; H2 pre-scaled by dinv[src] ----
__global__ __launch_bounds__(256)
void agg2_kernel(const u16* __restrict__ H2, const int* __restrict__ csr,
                 const int* __restrict__ row_start, const float* __restrict__ dinv,
                 const float* __restrict__ b2f, const int* __restrict__ ff,
                 void* __restrict__ out, int N) {
    int half = threadIdx.x >> 5;            // 0..7
    int c = threadIdx.x & 31;
    int n = blockIdx.x * 8 + half;
    if (n >= N) return;
    int s0 = row_start[n], s1 = row_start[n + 1];
    float acc = 0.f;
    for (int base = s0; base < s1; base += 32) {
        int m = s1 - base; if (m > 32) m = 32;
        int myidx = (c < m) ? csr[base + c] : 0;
        int j = 0;
        for (; j + 4 <= m; j += 4) {
            int i0 = __shfl(myidx, j, 32);
            int i1 = __shfl(myidx, j + 1, 32);
            int i2 = __shfl(myidx, j + 2, 32);
            int i3 = __shfl(myidx, j + 3, 32);
            float h0 = bf2f(H2[(size_t)i0 * 32 + c]);
            float h1 = bf2f(H2[(size_t)i1 * 32 + c]);
            float h2 = bf2f(H2[(size_t)i2 * 32 + c]);
            float h3 = bf2f(H2[(size_t)i3 * 32 + c]);
            acc += h0 + h1 + h2 + h3;
        }
        for (; j < m; ++j) {
            int s = __shfl(myidx, j, 32);
            acc += bf2f(H2[(size_t)s * 32 + c]);
        }
    }
    float tot = dinv[n] * acc + b2f[c];
    float mx = tot;
    #pragma unroll
    for (int m = 16; m; m >>= 1) mx = fmaxf(mx, __shfl_xor(mx, m, 32));
    float ex = expf(tot - mx);
    float sm = ex;
    #pragma unroll
    for (int m = 16; m; m >>= 1) sm += __shfl_xor(sm, m, 32);
    float r = tot - mx - logf(sm);
    if (*ff) ((float*)out)[(size_t)n * 32 + c] = r;
    else     ((u16*)out)[(size_t)n * 32 + c] = f2bf(r);
}

extern "C" void kernel_launch(void* const* d_in, const int* in_sizes, int n_in,
                              void* d_out, int out_size, void* d_ws, size_t ws_size,
                              hipStream_t stream) {
    const void* x  = d_in[0];
    const void* W1 = d_in[1];
    const void* b1 = d_in[2];
    const void* W2 = d_in[3];
    const void* b2 = d_in[4];
    const void* eb = d_in[5];

    const int HID  = in_sizes[2];            // 128
    const int CLS  = in_sizes[4];            // 32
    const int FEAT = in_sizes[1] / HID;      // 256
    const int N    = in_sizes[0] / FEAT;     // 100000
    const int E    = in_sizes[5] / 2;        // 1600000
    const int nb   = (N + BSZ - 1) >> BSH;   // 196 (assumes <= 256)
    (void)n_in; (void)out_size;

    char* w = (char*)d_ws;
    size_t p = 0;
    auto alloc = [&](size_t bytes) {
        size_t o = p; p = (p + bytes + 255) & ~(size_t)255; return o;
    };
    int*   flags      = (int*)  (w + alloc(32));
    int*   deg        = (int*)  (w + alloc((size_t)N * 4));
    int*   row_start  = (int*)  (w + alloc((size_t)(N + 1) * 4));
    int*   bsums      = (int*)  (w + alloc(512 * 4));
    int*   bucket_cnt = (int*)  (w + alloc(257 * 4));
    int*   bucket_base= (int*)  (w + alloc(257 * 4));
    int*   bucket_rsv = (int*)  (w + alloc(256 * 4));
    int*   bsrc       = (int*)  (w + alloc((size_t)E * 4));
    int*   bdst       = (int*)  (w + alloc((size_t)E * 4));
    int*   csr        = (int*)  (w + alloc((size_t)E * 4));
    float* dinv       = (float*)(w + alloc((size_t)N * 4));
    float* b1f        = (float*)(w + alloc((size_t)HID * 4));
    float* b2f        = (float*)(w + alloc((size_t)CLS * 4));
    u16*   B1p        = (u16*)  (w + alloc((size_t)FEAT * HID * 2));
    u16*   B2p        = (u16*)  (w + alloc((size_t)HID * CLS * 2));
    u16*   H          = (u16*)  (w + alloc((size_t)N * HID * 2));
    u16*   H1         = (u16*)  (w + alloc((size_t)N * HID * 2));
    u16*   H2         = (u16*)  (w + alloc((size_t)N * CLS * 2));
    if (p > ws_size) return;   // workspace too small: fail visibly

    detect_kernel<<<1, 256, 0, stream>>>((const u32*)x, (const int*)eb, flags);
    hipMemsetAsync(bucket_cnt, 0, 257 * 4, stream);
    bconv_kernel<<<1, 256, 0, stream>>>(b1, b2, flags, b1f, b2f, HID, CLS);

    hist_kernel<<<(E + 4095) / 4096, 256, 0, stream>>>(eb, flags, bucket_cnt, E, nb);
    bucket_scan_kernel<<<1, 256, 0, stream>>>(bucket_cnt, bucket_base, bucket_rsv, nb, E);
    passA_kernel<<<(E + 8191) / 8192, 256, 0, stream>>>(eb, flags, bucket_rsv,
                                                        bsrc, bdst, E, nb);
    degB_kernel<<<nb, 256, 0, stream>>>(bdst, bucket_base, deg, dinv, N);

    int nsb = (N + 255) / 256;
    scan_block_kernel<<<nsb, 256, 0, stream>>>(deg, row_start, bsums, N);
    scan_sums_kernel<<<1, 512, 0, stream>>>(bsums, nsb);
    scan_add_kernel<<<nsb, 256, 0, stream>>>(row_start, bsums, N, E);

    passB_kernel<<<nb, 256, 0, stream>>>(bsrc, bdst, bucket_base, row_start, csr);

    prepack_kernel<8, 8, 128><<<(8 * 8 * 64 * 8 + 255) / 256, 256, 0, stream>>>(W1, flags, B1p);
    prepack_kernel<2, 4, 32><<<(2 * 4 * 64 * 8 + 255) / 256, 256, 0, stream>>>(W2, flags, B2p);

    // G=2: 32 rows/wave, 128 rows/block
    int gblocks = (N + 127) / 128;
    gemm_kernel<8, 8, 2><<<gblocks, 256, 0, stream>>>(x, flags, B1p, dinv, H, N);
    agg1_kernel<<<(N + 3) / 4, 256, 0, stream>>>((const u32*)H, csr, row_start, dinv, b1f,
                                                 (u32*)H1, N);
    gemm_kernel<2, 4, 2><<<gblocks, 256, 0, stream>>>(H1, flags + 1, B2p, dinv, H2, N);
    agg2_kernel<<<(N + 7) / 8, 256, 0, stream>>>(H2, csr, row_start, dinv, b2f, flags,
                                                 (void*)d_out, N);
}

// Round 6
// 397.883 us; speedup vs baseline: 1.5931x; 1.0084x over previous
//
#include <hip/hip_runtime.h>

typedef unsigned short u16;
typedef unsigned int   u32;
typedef __attribute__((ext_vector_type(8))) short short8;
typedef __attribute__((ext_vector_type(4))) float f32x4;

constexpr int BSH = 9;               // bucket = dst >> 9  (512 dsts/bucket)
constexpr int BSZ = 1 << BSH;

__device__ inline float bf2f(u32 bits16) {
    union { u32 u; float f; } c; c.u = bits16 << 16; return c.f;
}
// round-half-up bf16 (cheap: add + shift); |err| <= 0.5 ulp like RNE
__device__ inline u16 f2bf(float f) {
    union { float f; u32 u; } c; c.f = f;
    return (u16)((c.u + 0x8000u) >> 16);
}
__device__ inline int ld_edge(const void* eb, int f64, size_t idx) {
    return f64 ? (int)((const long long*)eb)[idx] : ((const int*)eb)[idx];
}
// async global->LDS 16B per lane: LDS dest = s + lane*16 (wave-uniform s)
__device__ inline void async_cp16(const void* g, void* s) {
    __builtin_amdgcn_global_load_lds(
        (const __attribute__((address_space(1))) unsigned int*)g,
        (__attribute__((address_space(3))) unsigned int*)s, 16, 0, 0);
}

// ---------------- runtime dtype detection ----------------
// flags[0]: 1 => float inputs are fp32, 0 => bf16
// flags[1]: constant 0 — "ff" for internal bf16 GEMM inputs
// flags[2]: 1 => edge_index is int64, 0 => int32
__global__ void detect_kernel(const u32* xw, const int* ebuf_int, int* flags) {
    __shared__ int cnt;
    if (threadIdx.x == 0) cnt = 0;
    __syncthreads();
    u32 w = xw[threadIdx.x];
    int e = (int)((w >> 7) & 0xffu);   // bf16-pair: exponent of low element
    if (e >= 110 && e <= 145) atomicAdd(&cnt, 1);
    int ev = ebuf_int[2 * threadIdx.x + 1];
    unsigned long long any = __ballot(ev != 0);
    __syncthreads();
    if (threadIdx.x == 0) {
        flags[0] = (cnt < 192) ? 1 : 0;
        flags[1] = 0;
        flags[2] = (any == 0ULL) ? 1 : 0;
    }
}

// ---------------- bias convert to fp32 ----------------
__global__ void bconv_kernel(const void* b1, const void* b2, const int* flags,
                             float* b1f, float* b2f, int HID, int CLS) {
    int i = blockIdx.x * 256 + threadIdx.x;
    int f = flags[0];
    if (i < HID) b1f[i] = f ? ((const float*)b1)[i] : bf2f(((const u16*)b1)[i]);
    if (i < CLS) b2f[i] = f ? ((const float*)b2)[i] : bf2f(((const u16*)b2)[i]);
}

// ---------------- bucket histogram over dst (EPT=16) ----------------
__global__ void hist_kernel(const void* eb, const int* flags, int* bucket_cnt,
                            int E, int nb) {
    __shared__ int hist[256];
    hist[threadIdx.x] = 0;
    __syncthreads();
    int f64 = flags[2];
    int base = blockIdx.x * 4096;
    #pragma unroll
    for (int k = 0; k < 16; ++k) {
        int e = base + k * 256 + threadIdx.x;
        if (e < E) {
            int d = ld_edge(eb, f64, (size_t)E + e);
            atomicAdd(&hist[d >> BSH], 1);
        }
    }
    __syncthreads();
    int b = threadIdx.x;
    if (b < nb) { int c = hist[b]; if (c) atomicAdd(&bucket_cnt[b], c); }
}

// ---------------- bucket exclusive scan (nb <= 256) + cursor init ----------------
__global__ void bucket_scan_kernel(const int* bucket_cnt, int* bucket_base,
                                   int* bucket_rsv, int nb, int E) {
    __shared__ int wsum[4];
    int t = threadIdx.x, lane = t & 63, wv = t >> 6;
    int v = (t < nb) ? bucket_cnt[t] : 0;
    int inc = v;
    #pragma unroll
    for (int d = 1; d < 64; d <<= 1) {
        int tmp = __shfl_up(inc, d, 64);
        if (lane >= d) inc += tmp;
    }
    if (lane == 63) wsum[wv] = inc;
    __syncthreads();
    int off = 0;
    #pragma unroll
    for (int w = 0; w < 4; ++w) if (w < wv) off += wsum[w];
    int excl = off + inc - v;
    if (t <= nb) bucket_base[t] = (t == nb) ? E : excl;
    if (t < nb) bucket_rsv[t] = excl;
}

// ---------------- passA: scatter edges into dst-buckets (EPT=32) ----------------
__global__ __launch_bounds__(256)
void passA_kernel(const void* eb, const int* flags, int* bucket_rsv,
                  int* bsrc, int* bdst, int E, int nb) {
    __shared__ int hist[256];
    __shared__ int rbase[256];
    hist[threadIdx.x] = 0;
    __syncthreads();
    int f64 = flags[2];
    int base = blockIdx.x * 8192;
    #pragma unroll
    for (int k = 0; k < 32; ++k) {
        int e = base + k * 256 + threadIdx.x;
        if (e < E) {
            int d = ld_edge(eb, f64, (size_t)E + e);
            atomicAdd(&hist[d >> BSH], 1);
        }
    }
    __syncthreads();
    {
        int b = threadIdx.x;
        int c = (b < nb) ? hist[b] : 0;
        rbase[b] = c ? atomicAdd(&bucket_rsv[b], c) : 0;
        hist[b] = 0;
    }
    __syncthreads();
    #pragma unroll
    for (int k = 0; k < 32; ++k) {
        int e = base + k * 256 + threadIdx.x;
        if (e < E) {
            int d = ld_edge(eb, f64, (size_t)E + e);
            int s = ld_edge(eb, f64, (size_t)e);
            int bb = d >> BSH;
            int r = atomicAdd(&hist[bb], 1);
            int pos = rbase[bb] + r;
            bsrc[pos] = s;
            bdst[pos] = d;
        }
    }
}

// ------- degB: per-bucket degree count (LDS) -> deg + dinv, coalesced -------
__global__ __launch_bounds__(256)
void degB_kernel(const int* bdst, const int* bucket_base, int* deg, float* dinv, int N) {
    __shared__ int cur[BSZ];
    int b = blockIdx.x, d0 = b << BSH;
    for (int i = threadIdx.x; i < BSZ; i += 256) cur[i] = 0;
    __syncthreads();
    int e0 = bucket_base[b], e1 = bucket_base[b + 1];
    for (int e = e0 + threadIdx.x; e < e1; e += 256)
        atomicAdd(&cur[bdst[e] - d0], 1);
    __syncthreads();
    for (int i = threadIdx.x; i < BSZ; i += 256) {
        int d = d0 + i;
        if (d < N) {
            int c = cur[i];
            deg[d] = c;
            dinv[d] = (c > 0) ? 1.0f / sqrtf((float)c) : 0.0f;
        }
    }
}

// ---------------- passB: bucket -> csr (LDS cursor, local writes) ----------------
__global__ __launch_bounds__(256)
void passB_kernel(const int* bsrc, const int* bdst, const int* bucket_base,
                  const int* row_start, int* csr) {
    __shared__ int cur[BSZ];
    int b = blockIdx.x, d0 = b << BSH;
    for (int i = threadIdx.x; i < BSZ; i += 256) cur[i] = 0;
    __syncthreads();
    int e0 = bucket_base[b], e1 = bucket_base[b + 1];
    for (int e = e0 + threadIdx.x; e < e1; e += 256) {
        int d = bdst[e];
        int s = bsrc[e];
        int r = atomicAdd(&cur[d - d0], 1);
        csr[row_start[d] + r] = s;
    }
}

// ---------------- exclusive scan over deg (3 kernels) ----------------
__device__ inline int wave_incl_scan(int v, int lane) {
    #pragma unroll
    for (int d = 1; d < 64; d <<= 1) {
        int t = __shfl_up(v, d, 64);
        if (lane >= d) v += t;
    }
    return v;
}

__global__ void scan_block_kernel(const int* deg, int* row_start, int* bsums, int N) {
    __shared__ int wsum[4];
    int t = threadIdx.x, lane = t & 63, wv = t >> 6;
    int i = blockIdx.x * 256 + t;
    int v = (i < N) ? deg[i] : 0;
    int inc = wave_incl_scan(v, lane);
    if (lane == 63) wsum[wv] = inc;
    __syncthreads();
    int off = 0;
    #pragma unroll
    for (int w = 0; w < 4; ++w) if (w < wv) off += wsum[w];
    if (i < N) row_start[i] = off + inc - v;
    if (t == 255) bsums[blockIdx.x] = off + inc;
}

__global__ void scan_sums_kernel(int* bsums, int nb) {
    __shared__ int wsum[8];
    int t = threadIdx.x, lane = t & 63, wv = t >> 6;
    int v = (t < nb) ? bsums[t] : 0;
    int inc = wave_incl_scan(v, lane);
    if (lane == 63) wsum[wv] = inc;
    __syncthreads();
    int off = 0;
    #pragma unroll
    for (int w = 0; w < 8; ++w) if (w < wv) off += wsum[w];
    if (t < nb) bsums[t] = off + inc - v;   // exclusive
}

__global__ void scan_add_kernel(int* row_start, const int* bsums, int N, int E) {
    int i = blockIdx.x * 256 + threadIdx.x;
    if (i < N) row_start[i] += bsums[blockIdx.x];
    if (blockIdx.x == 0 && threadIdx.x == 0) row_start[N] = E;
}

// ------- weight prepack, nt-major (old order, for gemm2): ((nt*KT+kk)*64+lane)*8+j
template<int NT, int KT, int NCOLS>
__global__ void prepack_kernel(const void* W, const int* flags, u16* pack) {
    int p = blockIdx.x * 256 + threadIdx.x;
    constexpr int TOT = NT * KT * 64 * 8;
    if (p >= TOT) return;
    int j = p & 7, lane = (p >> 3) & 63, fk = p >> 9;
    int kk = fk % KT, nt = fk / KT;
    int n = nt * 16 + (lane & 15);
    int k = kk * 32 + (lane >> 4) * 8 + j;
    u16 v = flags[0] ? f2bf(((const float*)W)[k * NCOLS + n])
                     : ((const u16*)W)[k * NCOLS + n];
    pack[p] = v;
}

// ------- weight prepack, kk-major (for gemm1 slab staging): ((kk*NT+nt)*64+lane)*8+j
template<int NT, int KT, int NCOLS>
__global__ void prepackK_kernel(const void* W, const int* flags, u16* pack) {
    int p = blockIdx.x * 256 + threadIdx.x;
    constexpr int TOT = NT * KT * 64 * 8;
    if (p >= TOT) return;
    int j = p & 7, lane = (p >> 3) & 63, fk = p >> 9;
    int nt = fk % NT, kk = fk / NT;
    int n = nt * 16 + (lane & 15);
    int k = kk * 32 + (lane >> 4) * 8 + j;
    u16 v = flags[0] ? f2bf(((const float*)W)[k * NCOLS + n])
                     : ((const u16*)W)[k * NCOLS + n];
    pack[p] = v;
}

// ---- gemm1: LDS-staged dbuf K-loop. 128 rows/block, NT*16 cols, BK=32 ----
// A fp32 (or bf16) staged async into fragment-ordered LDS; B slab 8KB/step.
template<int NT, int KT>
__global__ __launch_bounds__(256)
void gemm1_kernel(const void* __restrict__ A, const int* __restrict__ ff,
                  const u16* __restrict__ Bpack, const float* __restrict__ dinv,
                  u16* __restrict__ C, int M) {
    constexpr int K = KT * 32;
    constexpr int Ncols = NT * 16;
    __shared__ char As[2][16384];
    __shared__ char Bs[2][8192];
    const bool fA = (*ff != 0);
    const int wave = threadIdx.x >> 6, lane = threadIdx.x & 63;
    const int r0 = blockIdx.x * 128;

    auto stage = [&](int kk, int buf) {
        if (fA) {
            // 16KB fp32 slab: chunk c (32B) = frag (rg,q,l16); lane pairs per chunk
            #pragma unroll
            for (int i = 0; i < 4; ++i) {
                int cb = (i * 4 + wave) * 32;
                int c = cb + (lane >> 1);
                int rg = c >> 6, rem = c & 63, q = rem >> 4, l16 = rem & 15;
                int row = r0 + rg * 16 + l16; if (row >= M) row = M - 1;
                const char* g = (const char*)A + (size_t)row * (K * 4)
                                + (kk * 32 + q * 8) * 4 + (lane & 1) * 16;
                async_cp16(g, &As[buf][(size_t)cb * 32]);
            }
        } else {
            // 8KB bf16 slab: chunk c (16B) = frag (rg,q,l16); one lane per chunk
            #pragma unroll
            for (int i = 0; i < 2; ++i) {
                int cb = (i * 4 + wave) * 64;
                int c = cb + lane;
                int rg = c >> 6, rem = c & 63, q = rem >> 4, l16 = rem & 15;
                int row = r0 + rg * 16 + l16; if (row >= M) row = M - 1;
                const char* g = (const char*)A + (size_t)row * (K * 2)
                                + (kk * 32 + q * 8) * 2;
                async_cp16(g, &As[buf][(size_t)cb * 16]);
            }
        }
        // B slab: linear 8KB copy (kk-major pack)
        #pragma unroll
        for (int i = 0; i < 2; ++i) {
            int off = (i * 4 + wave) * 1024;
            const char* g = (const char*)Bpack + (size_t)kk * (NT * 1024) + off
                            + (size_t)lane * 16;
            async_cp16(g, &Bs[buf][off]);
        }
    };

    const int q = lane >> 4, l16 = lane & 15;
    f32x4 acc[2][NT];
    #pragma unroll
    for (int g = 0; g < 2; ++g)
        #pragma unroll
        for (int nt = 0; nt < NT; ++nt) acc[g][nt] = (f32x4){0.f, 0.f, 0.f, 0.f};

    stage(0, 0);
    #pragma unroll
    for (int kk = 0; kk < KT; ++kk) {
        int cur = kk & 1;
        __syncthreads();                    // drains stage(kk) [vmcnt+lgkm]
        if (kk + 1 < KT) stage(kk + 1, cur ^ 1);   // async, overlaps compute
        short8 a[2];
        #pragma unroll
        for (int g = 0; g < 2; ++g) {
            int rg = wave * 2 + g;
            int fragidx = (rg * 4 + q) * 16 + l16;
            if (fA) {
                const f32x4* ap = (const f32x4*)&As[cur][(size_t)fragidx * 32];
                f32x4 v0 = ap[0];
                f32x4 v1 = ap[1];
                union { short8 s; u16 u[8]; } pa;
                pa.u[0] = f2bf(v0[0]); pa.u[1] = f2bf(v0[1]);
                pa.u[2] = f2bf(v0[2]); pa.u[3] = f2bf(v0[3]);
                pa.u[4] = f2bf(v1[0]); pa.u[5] = f2bf(v1[1]);
                pa.u[6] = f2bf(v1[2]); pa.u[7] = f2bf(v1[3]);
                a[g] = pa.s;
            } else {
                a[g] = *(const short8*)&As[cur][(size_t)fragidx * 16];
            }
        }
        #pragma unroll
        for (int nt = 0; nt < NT; ++nt) {
            short8 b = ((const short8*)Bs[cur])[nt * 64 + lane];
            acc[0][nt] = __builtin_amdgcn_mfma_f32_16x16x32_bf16(a[0], b, acc[0][nt], 0, 0, 0);
            acc[1][nt] = __builtin_amdgcn_mfma_f32_16x16x32_bf16(a[1], b, acc[1][nt], 0, 0, 0);
        }
    }
    #pragma unroll
    for (int g = 0; g < 2; ++g) {
        int mg = r0 + (wave * 2 + g) * 16;
        float sc[4];
        #pragma unroll
        for (int r = 0; r < 4; ++r) {
            int rr = mg + q * 4 + r;
            sc[r] = dinv[(rr < M) ? rr : (M - 1)];
        }
        #pragma unroll
        for (int nt = 0; nt < NT; ++nt) {
            int col = nt * 16 + l16;
            #pragma unroll
            for (int r = 0; r < 4; ++r) {
                int rrow = mg + q * 4 + r;
                if (rrow < M)
                    C[(size_t)rrow * Ncols + col] = f2bf(acc[g][nt][r] * sc[r]);
            }
        }
    }
}

// ---- gemm2 (old structure): A bf16 direct, B (nt-major) in LDS ----
template<int NT, int KT, int G>
__global__ __launch_bounds__(256)
void gemm_kernel(const void* __restrict__ A, const int* __restrict__ ff,
                 const u16* __restrict__ Bpack, const float* __restrict__ dinv,
                 u16* __restrict__ C, int M) {
    constexpr int K = KT * 32;
    constexpr int Ncols = NT * 16;
    __shared__ short8 lds[NT * KT * 64];
    for (int i = threadIdx.x; i < NT * KT * 64; i += 256)
        lds[i] = ((const short8*)Bpack)[i];
    bool fA = (*ff != 0);
    __syncthreads();
    int wave = threadIdx.x >> 6, lane = threadIdx.x & 63;
    int m0 = (blockIdx.x * 4 + wave) * (16 * G);
    if (m0 >= M) return;
    int q = lane >> 4;
    int rowc[G];
    #pragma unroll
    for (int g = 0; g < G; ++g) {
        int r = m0 + g * 16 + (lane & 15);
        rowc[g] = (r < M) ? r : (M - 1);
    }
    f32x4 acc[G][NT];
    #pragma unroll
    for (int g = 0; g < G; ++g)
        #pragma unroll
        for (int nt = 0; nt < NT; ++nt) acc[g][nt] = (f32x4){0.f, 0.f, 0.f, 0.f};
    #pragma unroll
    for (int kk = 0; kk < KT; ++kk) {
        short8 a[G];
        #pragma unroll
        for (int g = 0; g < G; ++g) {
            if (fA) {
                const float* Af = (const float*)A + (size_t)rowc[g] * K + kk * 32 + q * 8;
                f32x4 v0 = ((const f32x4*)Af)[0];
                f32x4 v1 = ((const f32x4*)Af)[1];
                union { short8 s; u16 u[8]; } pa;
                pa.u[0] = f2bf(v0[0]); pa.u[1] = f2bf(v0[1]);
                pa.u[2] = f2bf(v0[2]); pa.u[3] = f2bf(v0[3]);
                pa.u[4] = f2bf(v1[0]); pa.u[5] = f2bf(v1[1]);
                pa.u[6] = f2bf(v1[2]); pa.u[7] = f2bf(v1[3]);
                a[g] = pa.s;
            } else {
                a[g] = ((const short8*)((const u16*)A + (size_t)rowc[g] * K))[kk * 4 + q];
            }
        }
        #pragma unroll
        for (int nt = 0; nt < NT; ++nt) {
            short8 b = lds[(nt * KT + kk) * 64 + lane];
            #pragma unroll
            for (int g = 0; g < G; ++g)
                acc[g][nt] = __builtin_amdgcn_mfma_f32_16x16x32_bf16(a[g], b, acc[g][nt], 0, 0, 0);
        }
    }
    #pragma unroll
    for (int g = 0; g < G; ++g) {
        float sc[4];
        #pragma unroll
        for (int r = 0; r < 4; ++r) {
            int rr = m0 + g * 16 + q * 4 + r;
            sc[r] = dinv[(rr < M) ? rr : (M - 1)];
        }
        #pragma unroll
        for (int nt = 0; nt < NT; ++nt) {
            int col = nt * 16 + (lane & 15);
            #pragma unroll
            for (int r = 0; r < 4; ++r) {
                int rrow = m0 + g * 16 + q * 4 + r;
                if (rrow < M)
                    C[(size_t)rrow * Ncols + col] = f2bf(acc[g][nt][r] * sc[r]);
            }
        }
    }
}

// ---- layer-1 aggregation: H rows pre-scaled by dinv[src]; +bias, relu ----
__global__ __launch_bounds__(256)
void agg1_kernel(const u32* __restrict__ H32, const int* __restrict__ csr,
                 const int* __restrict__ row_start, const float* __restrict__ dinv,
                 const float* __restrict__ b1f, u32* __restrict__ H1, int N) {
    int wave = threadIdx.x >> 6, lane = threadIdx.x & 63;
    int n = blockIdx.x * 4 + wave;
    if (n >= N) return;
    int s0 = row_start[n], s1 = row_start[n + 1];
    float acc0 = 0.f, acc1 = 0.f;
    for (int base = s0; base < s1; base += 64) {
        int m = s1 - base; if (m > 64) m = 64;
        int myidx = (lane < m) ? csr[base + lane] : 0;
        int j = 0;
        for (; j + 4 <= m; j += 4) {
            int i0 = __shfl(myidx, j);
            int i1 = __shfl(myidx, j + 1);
            int i2 = __shfl(myidx, j + 2);
            int i3 = __shfl(myidx, j + 3);
            u32 h0 = H32[(size_t)i0 * 64 + lane];
            u32 h1 = H32[(size_t)i1 * 64 + lane];
            u32 h2 = H32[(size_t)i2 * 64 + lane];
            u32 h3 = H32[(size_t)i3 * 64 + lane];
            acc0 += bf2f(h0 & 0xffffu); acc1 += bf2f(h0 >> 16);
            acc0 += bf2f(h1 & 0xffffu); acc1 += bf2f(h1 >> 16);
            acc0 += bf2f(h2 & 0xffffu); acc1 += bf2f(h2 >> 16);
            acc0 += bf2f(h3 & 0xffffu); acc1 += bf2f(h3 >> 16);
        }
        for (; j < m; ++j) {
            int s = __shfl(myidx, j);
            u32 h = H32[(size_t)s * 64 + lane];
            acc0 += bf2f(h & 0xffffu); acc1 += bf2f(h >> 16);
        }
    }
    float wn = dinv[n];
    float v0 = fmaxf(wn * acc0 + b1f[2 * lane], 0.f);
    float v1 = fmaxf(wn * acc1 + b1f[2 * lane + 1], 0.f);
    H1[(size_t)n * 64 + lane] = (u32)f2bf(v0) | ((u32)f2bf(v1) << 16);
}

// ---- layer-2 aggregation + bias + log_softmax; H2 pre-scaled by dinv[src] ----
__global__ __launch_bounds__(256)
void agg2_kernel(const u16* __restrict__ H2, const int* __restrict__ csr,
                 const int* __restrict__ row_start, const float* __restrict__ dinv,
                 const float* __restrict__ b2f, const int* __restrict__ ff,
                 void* __restrict__ out, int N) {
    int half = threadIdx.x >> 5;            // 0..7
    int c = threadIdx.x & 31;
    int n = blockIdx.x * 8 + half;
    if (n >= N) return;
    int s0 = row_start[n], s1 = row_start[n + 1];
    float acc = 0.f;
    for (int base = s0; base < s1; base += 32) {
        int m = s1 - base; if (m > 32) m = 32;
        int myidx = (c < m) ? csr[base + c] : 0;
        int j = 0;
        for (; j + 4 <= m; j += 4) {
            int i0 = __shfl(myidx, j, 32);
            int i1 = __shfl(myidx, j + 1, 32);
            int i2 = __shfl(myidx, j + 2, 32);
            int i3 = __shfl(myidx, j + 3, 32);
            float h0 = bf2f(H2[(size_t)i0 * 32 + c]);
            float h1 = bf2f(H2[(size_t)i1 * 32 + c]);
            float h2 = bf2f(H2[(size_t)i2 * 32 + c]);
            float h3 = bf2f(H2[(size_t)i3 * 32 + c]);
            acc += h0 + h1 + h2 + h3;
        }
        for (; j < m; ++j) {
            int s = __shfl(myidx, j, 32);
            acc += bf2f(H2[(size_t)s * 32 + c]);
        }
    }
    float tot = dinv[n] * acc + b2f[c];
    float mx = tot;
    #pragma unroll
    for (int m = 16; m; m >>= 1) mx = fmaxf(mx, __shfl_xor(mx, m, 32));
    float ex = expf(tot - mx);
    float sm = ex;
    #pragma unroll
    for (int m = 16; m; m >>= 1) sm += __shfl_xor(sm, m, 32);
    float r = tot - mx - logf(sm);
    if (*ff) ((float*)out)[(size_t)n * 32 + c] = r;
    else     ((u16*)out)[(size_t)n * 32 + c] = f2bf(r);
}

extern "C" void kernel_launch(void* const* d_in, const int* in_sizes, int n_in,
                              void* d_out, int out_size, void* d_ws, size_t ws_size,
                              hipStream_t stream) {
    const void* x  = d_in[0];
    const void* W1 = d_in[1];
    const void* b1 = d_in[2];
    const void* W2 = d_in[3];
    const void* b2 = d_in[4];
    const void* eb = d_in[5];

    const int HID  = in_sizes[2];            // 128
    const int CLS  = in_sizes[4];            // 32
    const int FEAT = in_sizes[1] / HID;      // 256
    const int N    = in_sizes[0] / FEAT;     // 100000
    const int E    = in_sizes[5] / 2;        // 1600000
    const int nb   = (N + BSZ - 1) >> BSH;   // 196 (assumes <= 256)
    (void)n_in; (void)out_size;

    char* w = (char*)d_ws;
    size_t p = 0;
    auto alloc = [&](size_t bytes) {
        size_t o = p; p = (p + bytes + 255) & ~(size_t)255; return o;
    };
    int*   flags      = (int*)  (w + alloc(32));
    int*   deg        = (int*)  (w + alloc((size_t)N * 4));
    int*   row_start  = (int*)  (w + alloc((size_t)(N + 1) * 4));
    int*   bsums      = (int*)  (w + alloc(512 * 4));
    int*   bucket_cnt = (int*)  (w + alloc(257 * 4));
    int*   bucket_base= (int*)  (w + alloc(257 * 4));
    int*   bucket_rsv = (int*)  (w + alloc(256 * 4));
    int*   bsrc       = (int*)  (w + alloc((size_t)E * 4));
    int*   bdst       = (int*)  (w + alloc((size_t)E * 4));
    int*   csr        = (int*)  (w + alloc((size_t)E * 4));
    float* dinv       = (float*)(w + alloc((size_t)N * 4));
    float* b1f        = (float*)(w + alloc((size_t)HID * 4));
    float* b2f        = (float*)(w + alloc((size_t)CLS * 4));
    u16*   B1p        = (u16*)  (w + alloc((size_t)FEAT * HID * 2));
    u16*   B2p        = (u16*)  (w + alloc((size_t)HID * CLS * 2));
    u16*   H          = (u16*)  (w + alloc((size_t)N * HID * 2));
    u16*   H1         = (u16*)  (w + alloc((size_t)N * HID * 2));
    u16*   H2         = (u16*)  (w + alloc((size_t)N * CLS * 2));
    if (p > ws_size) return;   // workspace too small: fail visibly

    detect_kernel<<<1, 256, 0, stream>>>((const u32*)x, (const int*)eb, flags);
    hipMemsetAsync(bucket_cnt, 0, 257 * 4, stream);
    bconv_kernel<<<1, 256, 0, stream>>>(b1, b2, flags, b1f, b2f, HID, CLS);

    hist_kernel<<<(E + 4095) / 4096, 256, 0, stream>>>(eb, flags, bucket_cnt, E, nb);
    bucket_scan_kernel<<<1, 256, 0, stream>>>(bucket_cnt, bucket_base, bucket_rsv, nb, E);
    passA_kernel<<<(E + 8191) / 8192, 256, 0, stream>>>(eb, flags, bucket_rsv,
                                                        bsrc, bdst, E, nb);
    degB_kernel<<<nb, 256, 0, stream>>>(bdst, bucket_base, deg, dinv, N);

    int nsb = (N + 255) / 256;
    scan_block_kernel<<<nsb, 256, 0, stream>>>(deg, row_start, bsums, N);
    scan_sums_kernel<<<1, 512, 0, stream>>>(bsums, nsb);
    scan_add_kernel<<<nsb, 256, 0, stream>>>(row_start, bsums, N, E);

    passB_kernel<<<nb, 256, 0, stream>>>(bsrc, bdst, bucket_base, row_start, csr);

    prepackK_kernel<8, 8, 128><<<(8 * 8 * 64 * 8 + 255) / 256, 256, 0, stream>>>(W1, flags, B1p);
    prepack_kernel<2, 4, 32><<<(2 * 4 * 64 * 8 + 255) / 256, 256, 0, stream>>>(W2, flags, B2p);

    gemm1_kernel<8, 8><<<(N + 127) / 128, 256, 0, stream>>>(x, flags, B1p, dinv, H, N);
    agg1_kernel<<<(N + 3) / 4, 256, 0, stream>>>((const u32*)H, csr, row_start, dinv, b1f,
                                                 (u32*)H1, N);
    gemm_kernel<2, 4, 2><<<(N + 127) / 128, 256, 0, stream>>>(H1, flags + 1, B2p, dinv, H2, N);
    agg2_kernel<<<(N + 7) / 8, 256, 0, stream>>>(H2, csr, row_start, dinv, b2f, flags,
                                                 (void*)d_out, N);
}

// Round 7
// 393.852 us; speedup vs baseline: 1.6094x; 1.0102x over previous
//
#include <hip/hip_runtime.h>

typedef unsigned short u16;
typedef unsigned int   u32;
typedef __attribute__((ext_vector_type(8))) short short8;
typedef __attribute__((ext_vector_type(4))) float f32x4;

constexpr int BSH = 9;               // bucket = dst >> 9  (512 dsts/bucket)
constexpr int BSZ = 1 << BSH;

__device__ inline float bf2f(u32 bits16) {
    union { u32 u; float f; } c; c.u = bits16 << 16; return c.f;
}
// round-half-up bf16 (cheap: add + shift); |err| <= 0.5 ulp like RNE
__device__ inline u16 f2bf(float f) {
    union { float f; u32 u; } c; c.f = f;
    return (u16)((c.u + 0x8000u) >> 16);
}
__device__ inline int ld_edge(const void* eb, int f64, size_t idx) {
    return f64 ? (int)((const long long*)eb)[idx] : ((const int*)eb)[idx];
}
// async global->LDS 16B per lane: LDS dest = s + lane*16 (wave-uniform s)
__device__ inline void async_cp16(const void* g, void* s) {
    __builtin_amdgcn_global_load_lds(
        (const __attribute__((address_space(1))) unsigned int*)g,
        (__attribute__((address_space(3))) unsigned int*)s, 16, 0, 0);
}

// ---------------- runtime dtype detection ----------------
// flags[0]: 1 => float inputs are fp32, 0 => bf16
// flags[1]: constant 0 — "ff" for internal bf16 GEMM inputs
// flags[2]: 1 => edge_index is int64, 0 => int32
__global__ void detect_kernel(const u32* xw, const int* ebuf_int, int* flags) {
    __shared__ int cnt;
    if (threadIdx.x == 0) cnt = 0;
    __syncthreads();
    u32 w = xw[threadIdx.x];
    int e = (int)((w >> 7) & 0xffu);   // bf16-pair: exponent of low element
    if (e >= 110 && e <= 145) atomicAdd(&cnt, 1);
    int ev = ebuf_int[2 * threadIdx.x + 1];
    unsigned long long any = __ballot(ev != 0);
    __syncthreads();
    if (threadIdx.x == 0) {
        flags[0] = (cnt < 192) ? 1 : 0;
        flags[1] = 0;
        flags[2] = (any == 0ULL) ? 1 : 0;
    }
}

// ---------------- bias convert to fp32 ----------------
__global__ void bconv_kernel(const void* b1, const void* b2, const int* flags,
                             float* b1f, float* b2f, int HID, int CLS) {
    int i = blockIdx.x * 256 + threadIdx.x;
    int f = flags[0];
    if (i < HID) b1f[i] = f ? ((const float*)b1)[i] : bf2f(((const u16*)b1)[i]);
    if (i < CLS) b2f[i] = f ? ((const float*)b2)[i] : bf2f(((const u16*)b2)[i]);
}

// ---------------- bucket histogram over dst (EPT=16) ----------------
__global__ void hist_kernel(const void* eb, const int* flags, int* bucket_cnt,
                            int E, int nb) {
    __shared__ int hist[256];
    hist[threadIdx.x] = 0;
    __syncthreads();
    int f64 = flags[2];
    int base = blockIdx.x * 4096;
    #pragma unroll
    for (int k = 0; k < 16; ++k) {
        int e = base + k * 256 + threadIdx.x;
        if (e < E) {
            int d = ld_edge(eb, f64, (size_t)E + e);
            atomicAdd(&hist[d >> BSH], 1);
        }
    }
    __syncthreads();
    int b = threadIdx.x;
    if (b < nb) { int c = hist[b]; if (c) atomicAdd(&bucket_cnt[b], c); }
}

// ---------------- bucket exclusive scan (nb <= 256) + cursor init ----------------
__global__ void bucket_scan_kernel(const int* bucket_cnt, int* bucket_base,
                                   int* bucket_rsv, int nb, int E) {
    __shared__ int wsum[4];
    int t = threadIdx.x, lane = t & 63, wv = t >> 6;
    int v = (t < nb) ? bucket_cnt[t] : 0;
    int inc = v;
    #pragma unroll
    for (int d = 1; d < 64; d <<= 1) {
        int tmp = __shfl_up(inc, d, 64);
        if (lane >= d) inc += tmp;
    }
    if (lane == 63) wsum[wv] = inc;
    __syncthreads();
    int off = 0;
    #pragma unroll
    for (int w = 0; w < 4; ++w) if (w < wv) off += wsum[w];
    int excl = off + inc - v;
    if (t <= nb) bucket_base[t] = (t == nb) ? E : excl;
    if (t < nb) bucket_rsv[t] = excl;
}

// ---------------- passA: scatter edges into dst-buckets (EPT=32) ----------------
__global__ __launch_bounds__(256)
void passA_kernel(const void* eb, const int* flags, int* bucket_rsv,
                  int* bsrc, int* bdst, int E, int nb) {
    __shared__ int hist[256];
    __shared__ int rbase[256];
    hist[threadIdx.x] = 0;
    __syncthreads();
    int f64 = flags[2];
    int base = blockIdx.x * 8192;
    #pragma unroll
    for (int k = 0; k < 32; ++k) {
        int e = base + k * 256 + threadIdx.x;
        if (e < E) {
            int d = ld_edge(eb, f64, (size_t)E + e);
            atomicAdd(&hist[d >> BSH], 1);
        }
    }
    __syncthreads();
    {
        int b = threadIdx.x;
        int c = (b < nb) ? hist[b] : 0;
        rbase[b] = c ? atomicAdd(&bucket_rsv[b], c) : 0;
        hist[b] = 0;
    }
    __syncthreads();
    #pragma unroll
    for (int k = 0; k < 32; ++k) {
        int e = base + k * 256 + threadIdx.x;
        if (e < E) {
            int d = ld_edge(eb, f64, (size_t)E + e);
            int s = ld_edge(eb, f64, (size_t)e);
            int bb = d >> BSH;
            int r = atomicAdd(&hist[bb], 1);
            int pos = rbase[bb] + r;
            bsrc[pos] = s;
            bdst[pos] = d;
        }
    }
}

// ------- degB: per-bucket degree count (LDS) -> deg + dinv, coalesced -------
__global__ __launch_bounds__(256)
void degB_kernel(const int* bdst, const int* bucket_base, int* deg, float* dinv, int N) {
    __shared__ int cur[BSZ];
    int b = blockIdx.x, d0 = b << BSH;
    for (int i = threadIdx.x; i < BSZ; i += 256) cur[i] = 0;
    __syncthreads();
    int e0 = bucket_base[b], e1 = bucket_base[b + 1];
    for (int e = e0 + threadIdx.x; e < e1; e += 256)
        atomicAdd(&cur[bdst[e] - d0], 1);
    __syncthreads();
    for (int i = threadIdx.x; i < BSZ; i += 256) {
        int d = d0 + i;
        if (d < N) {
            int c = cur[i];
            deg[d] = c;
            dinv[d] = (c > 0) ? 1.0f / sqrtf((float)c) : 0.0f;
        }
    }
}

// ---------------- passB: bucket -> csr (LDS cursor, local writes) ----------------
__global__ __launch_bounds__(256)
void passB_kernel(const int* bsrc, const int* bdst, const int* bucket_base,
                  const int* row_start, int* csr) {
    __shared__ int cur[BSZ];
    int b = blockIdx.x, d0 = b << BSH;
    for (int i = threadIdx.x; i < BSZ; i += 256) cur[i] = 0;
    __syncthreads();
    int e0 = bucket_base[b], e1 = bucket_base[b + 1];
    for (int e = e0 + threadIdx.x; e < e1; e += 256) {
        int d = bdst[e];
        int s = bsrc[e];
        int r = atomicAdd(&cur[d - d0], 1);
        csr[row_start[d] + r] = s;
    }
}

// ---------------- exclusive scan over deg (3 kernels) ----------------
__device__ inline int wave_incl_scan(int v, int lane) {
    #pragma unroll
    for (int d = 1; d < 64; d <<= 1) {
        int t = __shfl_up(v, d, 64);
        if (lane >= d) v += t;
    }
    return v;
}

__global__ void scan_block_kernel(const int* deg, int* row_start, int* bsums, int N) {
    __shared__ int wsum[4];
    int t = threadIdx.x, lane = t & 63, wv = t >> 6;
    int i = blockIdx.x * 256 + t;
    int v = (i < N) ? deg[i] : 0;
    int inc = wave_incl_scan(v, lane);
    if (lane == 63) wsum[wv] = inc;
    __syncthreads();
    int off = 0;
    #pragma unroll
    for (int w = 0; w < 4; ++w) if (w < wv) off += wsum[w];
    if (i < N) row_start[i] = off + inc - v;
    if (t == 255) bsums[blockIdx.x] = off + inc;
}

__global__ void scan_sums_kernel(int* bsums, int nb) {
    __shared__ int wsum[8];
    int t = threadIdx.x, lane = t & 63, wv = t >> 6;
    int v = (t < nb) ? bsums[t] : 0;
    int inc = wave_incl_scan(v, lane);
    if (lane == 63) wsum[wv] = inc;
    __syncthreads();
    int off = 0;
    #pragma unroll
    for (int w = 0; w < 8; ++w) if (w < wv) off += wsum[w];
    if (t < nb) bsums[t] = off + inc - v;   // exclusive
}

__global__ void scan_add_kernel(int* row_start, const int* bsums, int N, int E) {
    int i = blockIdx.x * 256 + threadIdx.x;
    if (i < N) row_start[i] += bsums[blockIdx.x];
    if (blockIdx.x == 0 && threadIdx.x == 0) row_start[N] = E;
}

// ------- weight prepack, nt-major (old order, for gemm2): ((nt*KT+kk)*64+lane)*8+j
template<int NT, int KT, int NCOLS>
__global__ void prepack_kernel(const void* W, const int* flags, u16* pack) {
    int p = blockIdx.x * 256 + threadIdx.x;
    constexpr int TOT = NT * KT * 64 * 8;
    if (p >= TOT) return;
    int j = p & 7, lane = (p >> 3) & 63, fk = p >> 9;
    int kk = fk % KT, nt = fk / KT;
    int n = nt * 16 + (lane & 15);
    int k = kk * 32 + (lane >> 4) * 8 + j;
    u16 v = flags[0] ? f2bf(((const float*)W)[k * NCOLS + n])
                     : ((const u16*)W)[k * NCOLS + n];
    pack[p] = v;
}

// ------- weight prepack, kk-major (for gemm1 slab staging): ((kk*NT+nt)*64+lane)*8+j
template<int NT, int KT, int NCOLS>
__global__ void prepackK_kernel(const void* W, const int* flags, u16* pack) {
    int p = blockIdx.x * 256 + threadIdx.x;
    constexpr int TOT = NT * KT * 64 * 8;
    if (p >= TOT) return;
    int j = p & 7, lane = (p >> 3) & 63, fk = p >> 9;
    int nt = fk % NT, kk = fk / NT;
    int n = nt * 16 + (lane & 15);
    int k = kk * 32 + (lane >> 4) * 8 + j;
    u16 v = flags[0] ? f2bf(((const float*)W)[k * NCOLS + n])
                     : ((const u16*)W)[k * NCOLS + n];
    pack[p] = v;
}

// ---- gemm1: LDS-staged dbuf K-loop, N-split. 128 rows x NT*16 cols per block ----
// NTF = full col-tile count in Bpack (kk-major); each block handles NT of them.
// LDS: As dbuf 32KB (fp32) + Bs dbuf 2*NT KB  => 40KB @ NT=4 -> 4 blocks/CU.
template<int NT, int NTF, int KT>
__global__ __launch_bounds__(256)
void gemm1_kernel(const void* __restrict__ A, const int* __restrict__ ff,
                  const u16* __restrict__ Bpack, const float* __restrict__ dinv,
                  u16* __restrict__ C, int M) {
    constexpr int K = KT * 32;
    constexpr int Ncols = NTF * 16;
    constexpr int NSPLIT = NTF / NT;
    __shared__ char As[2][16384];
    __shared__ char Bs[2][NT * 1024];
    const bool fA = (*ff != 0);
    const int wave = threadIdx.x >> 6, lane = threadIdx.x & 63;
    const int bh = blockIdx.x % NSPLIT;          // column half
    const int r0 = (blockIdx.x / NSPLIT) * 128;  // row stripe

    auto stage = [&](int kk, int buf) {
        if (fA) {
            // 16KB fp32 slab: chunk c (32B) = frag (rg,q,l16); lane pairs per chunk
            #pragma unroll
            for (int i = 0; i < 4; ++i) {
                int cb = (i * 4 + wave) * 32;
                int c = cb + (lane >> 1);
                int rg = c >> 6, rem = c & 63, q = rem >> 4, l16 = rem & 15;
                int row = r0 + rg * 16 + l16; if (row >= M) row = M - 1;
                const char* g = (const char*)A + (size_t)row * (K * 4)
                                + (kk * 32 + q * 8) * 4 + (lane & 1) * 16;
                async_cp16(g, &As[buf][(size_t)cb * 32]);
            }
        } else {
            // 8KB bf16 slab: chunk c (16B) = frag (rg,q,l16); one lane per chunk
            #pragma unroll
            for (int i = 0; i < 2; ++i) {
                int cb = (i * 4 + wave) * 64;
                int c = cb + lane;
                int rg = c >> 6, rem = c & 63, q = rem >> 4, l16 = rem & 15;
                int row = r0 + rg * 16 + l16; if (row >= M) row = M - 1;
                const char* g = (const char*)A + (size_t)row * (K * 2)
                                + (kk * 32 + q * 8) * 2;
                async_cp16(g, &As[buf][(size_t)cb * 16]);
            }
        }
        // B slice: NT KB linear copy from kk-major pack (full row NTF KB)
        if (wave < NT) {
            int off = wave * 1024;
            const char* g = (const char*)Bpack + (size_t)kk * (NTF * 1024)
                            + (size_t)bh * (NT * 1024) + off + (size_t)lane * 16;
            async_cp16(g, &Bs[buf][off]);
        }
    };

    const int q = lane >> 4, l16 = lane & 15;
    f32x4 acc[2][NT];
    #pragma unroll
    for (int g = 0; g < 2; ++g)
        #pragma unroll
        for (int nt = 0; nt < NT; ++nt) acc[g][nt] = (f32x4){0.f, 0.f, 0.f, 0.f};

    stage(0, 0);
    #pragma unroll
    for (int kk = 0; kk < KT; ++kk) {
        int cur = kk & 1;
        __syncthreads();                    // drains stage(kk) [vmcnt+lgkm]
        if (kk + 1 < KT) stage(kk + 1, cur ^ 1);   // async, overlaps compute
        short8 a[2];
        #pragma unroll
        for (int g = 0; g < 2; ++g) {
            int rg = wave * 2 + g;
            int fragidx = (rg * 4 + q) * 16 + l16;
            if (fA) {
                const f32x4* ap = (const f32x4*)&As[cur][(size_t)fragidx * 32];
                f32x4 v0 = ap[0];
                f32x4 v1 = ap[1];
                union { short8 s; u16 u[8]; } pa;
                pa.u[0] = f2bf(v0[0]); pa.u[1] = f2bf(v0[1]);
                pa.u[2] = f2bf(v0[2]); pa.u[3] = f2bf(v0[3]);
                pa.u[4] = f2bf(v1[0]); pa.u[5] = f2bf(v1[1]);
                pa.u[6] = f2bf(v1[2]); pa.u[7] = f2bf(v1[3]);
                a[g] = pa.s;
            } else {
                a[g] = *(const short8*)&As[cur][(size_t)fragidx * 16];
            }
        }
        #pragma unroll
        for (int nt = 0; nt < NT; ++nt) {
            short8 b = ((const short8*)Bs[cur])[nt * 64 + lane];
            acc[0][nt] = __builtin_amdgcn_mfma_f32_16x16x32_bf16(a[0], b, acc[0][nt], 0, 0, 0);
            acc[1][nt] = __builtin_amdgcn_mfma_f32_16x16x32_bf16(a[1], b, acc[1][nt], 0, 0, 0);
        }
    }
    #pragma unroll
    for (int g = 0; g < 2; ++g) {
        int mg = r0 + (wave * 2 + g) * 16;
        float sc[4];
        #pragma unroll
        for (int r = 0; r < 4; ++r) {
            int rr = mg + q * 4 + r;
            sc[r] = dinv[(rr < M) ? rr : (M - 1)];
        }
        #pragma unroll
        for (int nt = 0; nt < NT; ++nt) {
            int col = bh * (NT * 16) + nt * 16 + l16;
            #pragma unroll
            for (int r = 0; r < 4; ++r) {
                int rrow = mg + q * 4 + r;
                if (rrow < M)
                    C[(size_t)rrow * Ncols + col] = f2bf(acc[g][nt][r] * sc[r]);
            }
        }
    }
}

// ---- gemm2 (old structure): A bf16 direct, B (nt-major) in LDS ----
template<int NT, int KT, int G>
__global__ __launch_bounds__(256)
void gemm_kernel(const void* __restrict__ A, const int* __restrict__ ff,
                 const u16* __restrict__ Bpack, const float* __restrict__ dinv,
                 u16* __restrict__ C, int M) {
    constexpr int K = KT * 32;
    constexpr int Ncols = NT * 16;
    __shared__ short8 lds[NT * KT * 64];
    for (int i = threadIdx.x; i < NT * KT * 64; i += 256)
        lds[i] = ((const short8*)Bpack)[i];
    bool fA = (*ff != 0);
    __syncthreads();
    int wave = threadIdx.x >> 6, lane = threadIdx.x & 63;
    int m0 = (blockIdx.x * 4 + wave) * (16 * G);
    if (m0 >= M) return;
    int q = lane >> 4;
    int rowc[G];
    #pragma unroll
    for (int g = 0; g < G; ++g) {
        int r = m0 + g * 16 + (lane & 15);
        rowc[g] = (r < M) ? r : (M - 1);
    }
    f32x4 acc[G][NT];
    #pragma unroll
    for (int g = 0; g < G; ++g)
        #pragma unroll
        for (int nt = 0; nt < NT; ++nt) acc[g][nt] = (f32x4){0.f, 0.f, 0.f, 0.f};
    #pragma unroll
    for (int kk = 0; kk < KT; ++kk) {
        short8 a[G];
        #pragma unroll
        for (int g = 0; g < G; ++g) {
            if (fA) {
                const float* Af = (const float*)A + (size_t)rowc[g] * K + kk * 32 + q * 8;
                f32x4 v0 = ((const f32x4*)Af)[0];
                f32x4 v1 = ((const f32x4*)Af)[1];
                union { short8 s; u16 u[8]; } pa;
                pa.u[0] = f2bf(v0[0]); pa.u[1] = f2bf(v0[1]);
                pa.u[2] = f2bf(v0[2]); pa.u[3] = f2bf(v0[3]);
                pa.u[4] = f2bf(v1[0]); pa.u[5] = f2bf(v1[1]);
                pa.u[6] = f2bf(v1[2]); pa.u[7] = f2bf(v1[3]);
                a[g] = pa.s;
            } else {
                a[g] = ((const short8*)((const u16*)A + (size_t)rowc[g] * K))[kk * 4 + q];
            }
        }
        #pragma unroll
        for (int nt = 0; nt < NT; ++nt) {
            short8 b = lds[(nt * KT + kk) * 64 + lane];
            #pragma unroll
            for (int g = 0; g < G; ++g)
                acc[g][nt] = __builtin_amdgcn_mfma_f32_16x16x32_bf16(a[g], b, acc[g][nt], 0, 0, 0);
        }
    }
    #pragma unroll
    for (int g = 0; g < G; ++g) {
        float sc[4];
        #pragma unroll
        for (int r = 0; r < 4; ++r) {
            int rr = m0 + g * 16 + q * 4 + r;
            sc[r] = dinv[(rr < M) ? rr : (M - 1)];
        }
        #pragma unroll
        for (int nt = 0; nt < NT; ++nt) {
            int col = nt * 16 + (lane & 15);
            #pragma unroll
            for (int r = 0; r < 4; ++r) {
                int rrow = m0 + g * 16 + q * 4 + r;
                if (rrow < M)
                    C[(size_t)rrow * Ncols + col] = f2bf(acc[g][nt][r] * sc[r]);
            }
        }
    }
}

// ---- layer-1 aggregation: H rows pre-scaled by dinv[src]; +bias, relu ----
__global__ __launch_bounds__(256)
void agg1_kernel(const u32* __restrict__ H32, const int* __restrict__ csr,
                 const int* __restrict__ row_start, const float* __restrict__ dinv,
                 const float* __restrict__ b1f, u32* __restrict__ H1, int N) {
    int wave = threadIdx.x >> 6, lane = threadIdx.x & 63;
    int n = blockIdx.x * 4 + wave;
    if (n >= N) return;
    int s0 = row_start[n], s1 = row_start[n + 1];
    float acc0 = 0.f, acc1 = 0.f;
    for (int base = s0; base < s1; base += 64) {
        int m = s1 - base; if (m > 64) m = 64;
        int myidx = (lane < m) ? csr[base + lane] : 0;
        int j = 0;
        for (; j + 4 <= m; j += 4) {
            int i0 = __shfl(myidx, j);
            int i1 = __shfl(myidx, j + 1);
            int i2 = __shfl(myidx, j + 2);
            int i3 = __shfl(myidx, j + 3);
            u32 h0 = H32[(size_t)i0 * 64 + lane];
            u32 h1 = H32[(size_t)i1 * 64 + lane];
            u32 h2 = H32[(size_t)i2 * 64 + lane];
            u32 h3 = H32[(size_t)i3 * 64 + lane];
            acc0 += bf2f(h0 & 0xffffu); acc1 += bf2f(h0 >> 16);
            acc0 += bf2f(h1 & 0xffffu); acc1 += bf2f(h1 >> 16);
            acc0 += bf2f(h2 & 0xffffu); acc1 += bf2f(h2 >> 16);
            acc0 += bf2f(h3 & 0xffffu); acc1 += bf2f(h3 >> 16);
        }
        for (; j < m; ++j) {
            int s = __shfl(myidx, j);
            u32 h = H32[(size_t)s * 64 + lane];
            acc0 += bf2f(h & 0xffffu); acc1 += bf2f(h >> 16);
        }
    }
    float wn = dinv[n];
    float v0 = fmaxf(wn * acc0 + b1f[2 * lane], 0.f);
    float v1 = fmaxf(wn * acc1 + b1f[2 * lane + 1], 0.f);
    H1[(size_t)n * 64 + lane] = (u32)f2bf(v0) | ((u32)f2bf(v1) << 16);
}

// ---- layer-2 aggregation + bias + log_softmax; H2 pre-scaled by dinv[src] ----
__global__ __launch_bounds__(256)
void agg2_kernel(const u16* __restrict__ H2, const int* __restrict__ csr,
                 const int* __restrict__ row_start, const float* __restrict__ dinv,
                 const float* __restrict__ b2f, const int* __restrict__ ff,
                 void* __restrict__ out, int N) {
    int half = threadIdx.x >> 5;            // 0..7
    int c = threadIdx.x & 31;
    int n = blockIdx.x * 8 + half;
    if (n >= N) return;
    int s0 = row_start[n], s1 = row_start[n + 1];
    float acc = 0.f;
    for (int base = s0; base < s1; base += 32) {
        int m = s1 - base; if (m > 32) m = 32;
        int myidx = (c < m) ? csr[base + c] : 0;
        int j = 0;
        for (; j + 4 <= m; j += 4) {
            int i0 = __shfl(myidx, j, 32);
            int i1 = __shfl(myidx, j + 1, 32);
            int i2 = __shfl(myidx, j + 2, 32);
            int i3 = __shfl(myidx, j + 3, 32);
            float h0 = bf2f(H2[(size_t)i0 * 32 + c]);
            float h1 = bf2f(H2[(size_t)i1 * 32 + c]);
            float h2 = bf2f(H2[(size_t)i2 * 32 + c]);
            float h3 = bf2f(H2[(size_t)i3 * 32 + c]);
            acc += h0 + h1 + h2 + h3;
        }
        for (; j < m; ++j) {
            int s = __shfl(myidx, j, 32);
            acc += bf2f(H2[(size_t)s * 32 + c]);
        }
    }
    float tot = dinv[n] * acc + b2f[c];
    float mx = tot;
    #pragma unroll
    for (int m = 16; m; m >>= 1) mx = fmaxf(mx, __shfl_xor(mx, m, 32));
    float ex = expf(tot - mx);
    float sm = ex;
    #pragma unroll
    for (int m = 16; m; m >>= 1) sm += __shfl_xor(sm, m, 32);
    float r = tot - mx - logf(sm);
    if (*ff) ((float*)out)[(size_t)n * 32 + c] = r;
    else     ((u16*)out)[(size_t)n * 32 + c] = f2bf(r);
}

extern "C" void kernel_launch(void* const* d_in, const int* in_sizes, int n_in,
                              void* d_out, int out_size, void* d_ws, size_t ws_size,
                              hipStream_t stream) {
    const void* x  = d_in[0];
    const void* W1 = d_in[1];
    const void* b1 = d_in[2];
    const void* W2 = d_in[3];
    const void* b2 = d_in[4];
    const void* eb = d_in[5];

    const int HID  = in_sizes[2];            // 128
    const int CLS  = in_sizes[4];            // 32
    const int FEAT = in_sizes[1] / HID;      // 256
    const int N    = in_sizes[0] / FEAT;     // 100000
    const int E    = in_sizes[5] / 2;        // 1600000
    const int nb   = (N + BSZ - 1) >> BSH;   // 196 (assumes <= 256)
    (void)n_in; (void)out_size;

    char* w = (char*)d_ws;
    size_t p = 0;
    auto alloc = [&](size_t bytes) {
        size_t o = p; p = (p + bytes + 255) & ~(size_t)255; return o;
    };
    int*   flags      = (int*)  (w + alloc(32));
    int*   deg        = (int*)  (w + alloc((size_t)N * 4));
    int*   row_start  = (int*)  (w + alloc((size_t)(N + 1) * 4));
    int*   bsums      = (int*)  (w + alloc(512 * 4));
    int*   bucket_cnt = (int*)  (w + alloc(257 * 4));
    int*   bucket_base= (int*)  (w + alloc(257 * 4));
    int*   bucket_rsv = (int*)  (w + alloc(256 * 4));
    int*   bsrc       = (int*)  (w + alloc((size_t)E * 4));
    int*   bdst       = (int*)  (w + alloc((size_t)E * 4));
    int*   csr        = (int*)  (w + alloc((size_t)E * 4));
    float* dinv       = (float*)(w + alloc((size_t)N * 4));
    float* b1f        = (float*)(w + alloc((size_t)HID * 4));
    float* b2f        = (float*)(w + alloc((size_t)CLS * 4));
    u16*   B1p        = (u16*)  (w + alloc((size_t)FEAT * HID * 2));
    u16*   B2p        = (u16*)  (w + alloc((size_t)HID * CLS * 2));
    u16*   H          = (u16*)  (w + alloc((size_t)N * HID * 2));
    u16*   H1         = (u16*)  (w + alloc((size_t)N * HID * 2));
    u16*   H2         = (u16*)  (w + alloc((size_t)N * CLS * 2));
    if (p > ws_size) return;   // workspace too small: fail visibly

    detect_kernel<<<1, 256, 0, stream>>>((const u32*)x, (const int*)eb, flags);
    hipMemsetAsync(bucket_cnt, 0, 257 * 4, stream);
    bconv_kernel<<<1, 256, 0, stream>>>(b1, b2, flags, b1f, b2f, HID, CLS);

    hist_kernel<<<(E + 4095) / 4096, 256, 0, stream>>>(eb, flags, bucket_cnt, E, nb);
    bucket_scan_kernel<<<1, 256, 0, stream>>>(bucket_cnt, bucket_base, bucket_rsv, nb, E);
    passA_kernel<<<(E + 8191) / 8192, 256, 0, stream>>>(eb, flags, bucket_rsv,
                                                        bsrc, bdst, E, nb);
    degB_kernel<<<nb, 256, 0, stream>>>(bdst, bucket_base, deg, dinv, N);

    int nsb = (N + 255) / 256;
    scan_block_kernel<<<nsb, 256, 0, stream>>>(deg, row_start, bsums, N);
    scan_sums_kernel<<<1, 512, 0, stream>>>(bsums, nsb);
    scan_add_kernel<<<nsb, 256, 0, stream>>>(row_start, bsums, N, E);

    passB_kernel<<<nb, 256, 0, stream>>>(bsrc, bdst, bucket_base, row_start, csr);

    prepackK_kernel<8, 8, 128><<<(8 * 8 * 64 * 8 + 255) / 256, 256, 0, stream>>>(W1, flags, B1p);
    prepack_kernel<2, 4, 32><<<(2 * 4 * 64 * 8 + 255) / 256, 256, 0, stream>>>(W2, flags, B2p);

    // gemm1: N-split in 2 col-halves (NT=4 of NTF=8), 128-row stripes
    gemm1_kernel<4, 8, 8><<<2 * ((N + 127) / 128), 256, 0, stream>>>(x, flags, B1p, dinv, H, N);
    agg1_kernel<<<(N + 3) / 4, 256, 0, stream>>>((const u32*)H, csr, row_start, dinv, b1f,
                                                 (u32*)H1, N);
    gemm_kernel<2, 4, 2><<<(N + 127) / 128, 256, 0, stream>>>(H1, flags + 1, B2p, dinv, H2, N);
    agg2_kernel<<<(N + 7) / 8, 256, 0, stream>>>(H2, csr, row_start, dinv, b2f, flags,
                                                 (void*)d_out, N);
}

// Round 8
// 389.865 us; speedup vs baseline: 1.6259x; 1.0102x over previous
//
#include <hip/hip_runtime.h>

typedef unsigned short u16;
typedef unsigned int   u32;
typedef __attribute__((ext_vector_type(8))) short short8;
typedef __attribute__((ext_vector_type(4))) float f32x4;
typedef __attribute__((ext_vector_type(2))) float f32x2;

constexpr int BSH = 9;               // bucket = dst >> 9  (512 dsts/bucket)
constexpr int BSZ = 1 << BSH;

__device__ inline float bf2f(u32 bits16) {
    union { u32 u; float f; } c; c.u = bits16 << 16; return c.f;
}
// round-half-up bf16 (cheap: add + shift); |err| <= 0.5 ulp like RNE
__device__ inline u16 f2bf(float f) {
    union { float f; u32 u; } c; c.f = f;
    return (u16)((c.u + 0x8000u) >> 16);
}
// unpack bf16-pair word into float2 (lo, hi) — 2 bit-ops, adds can go packed
__device__ inline f32x2 up2(u32 h) {
    union { u32 u[2]; f32x2 f; } c;
    c.u[0] = h << 16;
    c.u[1] = h & 0xffff0000u;
    return c.f;
}
__device__ inline int ld_edge(const void* eb, int f64, size_t idx) {
    return f64 ? (int)((const long long*)eb)[idx] : ((const int*)eb)[idx];
}

// ---------------- runtime dtype detection ----------------
__global__ void detect_kernel(const u32* xw, const int* ebuf_int, int* flags) {
    __shared__ int cnt;
    if (threadIdx.x == 0) cnt = 0;
    __syncthreads();
    u32 w = xw[threadIdx.x];
    int e = (int)((w >> 7) & 0xffu);   // bf16-pair: exponent of low element
    if (e >= 110 && e <= 145) atomicAdd(&cnt, 1);
    int ev = ebuf_int[2 * threadIdx.x + 1];
    unsigned long long any = __ballot(ev != 0);
    __syncthreads();
    if (threadIdx.x == 0) {
        flags[0] = (cnt < 192) ? 1 : 0;
        flags[1] = 0;
        flags[2] = (any == 0ULL) ? 1 : 0;
    }
}

// ---------------- bias convert to fp32 ----------------
__global__ void bconv_kernel(const void* b1, const void* b2, const int* flags,
                             float* b1f, float* b2f, int HID, int CLS) {
    int i = blockIdx.x * 256 + threadIdx.x;
    int f = flags[0];
    if (i < HID) b1f[i] = f ? ((const float*)b1)[i] : bf2f(((const u16*)b1)[i]);
    if (i < CLS) b2f[i] = f ? ((const float*)b2)[i] : bf2f(((const u16*)b2)[i]);
}

// ---------------- bucket histogram over dst (EPT=16) ----------------
__global__ void hist_kernel(const void* eb, const int* flags, int* bucket_cnt,
                            int E, int nb) {
    __shared__ int hist[256];
    hist[threadIdx.x] = 0;
    __syncthreads();
    int f64 = flags[2];
    int base = blockIdx.x * 4096;
    #pragma unroll
    for (int k = 0; k < 16; ++k) {
        int e = base + k * 256 + threadIdx.x;
        if (e < E) {
            int d = ld_edge(eb, f64, (size_t)E + e);
            atomicAdd(&hist[d >> BSH], 1);
        }
    }
    __syncthreads();
    int b = threadIdx.x;
    if (b < nb) { int c = hist[b]; if (c) atomicAdd(&bucket_cnt[b], c); }
}

// ---------------- bucket exclusive scan (nb <= 256) + cursor init ----------------
__global__ void bucket_scan_kernel(const int* bucket_cnt, int* bucket_base,
                                   int* bucket_rsv, int nb, int E) {
    __shared__ int wsum[4];
    int t = threadIdx.x, lane = t & 63, wv = t >> 6;
    int v = (t < nb) ? bucket_cnt[t] : 0;
    int inc = v;
    #pragma unroll
    for (int d = 1; d < 64; d <<= 1) {
        int tmp = __shfl_up(inc, d, 64);
        if (lane >= d) inc += tmp;
    }
    if (lane == 63) wsum[wv] = inc;
    __syncthreads();
    int off = 0;
    #pragma unroll
    for (int w = 0; w < 4; ++w) if (w < wv) off += wsum[w];
    int excl = off + inc - v;
    if (t <= nb) bucket_base[t] = (t == nb) ? E : excl;
    if (t < nb) bucket_rsv[t] = excl;
}

// ---------------- passA: scatter edges into dst-buckets (EPT=32) ----------------
__global__ __launch_bounds__(256)
void passA_kernel(const void* eb, const int* flags, int* bucket_rsv,
                  int* bsrc, int* bdst, int E, int nb) {
    __shared__ int hist[256];
    __shared__ int rbase[256];
    hist[threadIdx.x] = 0;
    __syncthreads();
    int f64 = flags[2];
    int base = blockIdx.x * 8192;
    #pragma unroll
    for (int k = 0; k < 32; ++k) {
        int e = base + k * 256 + threadIdx.x;
        if (e < E) {
            int d = ld_edge(eb, f64, (size_t)E + e);
            atomicAdd(&hist[d >> BSH], 1);
        }
    }
    __syncthreads();
    {
        int b = threadIdx.x;
        int c = (b < nb) ? hist[b] : 0;
        rbase[b] = c ? atomicAdd(&bucket_rsv[b], c) : 0;
        hist[b] = 0;
    }
    __syncthreads();
    #pragma unroll
    for (int k = 0; k < 32; ++k) {
        int e = base + k * 256 + threadIdx.x;
        if (e < E) {
            int d = ld_edge(eb, f64, (size_t)E + e);
            int s = ld_edge(eb, f64, (size_t)e);
            int bb = d >> BSH;
            int r = atomicAdd(&hist[bb], 1);
            int pos = rbase[bb] + r;
            bsrc[pos] = s;
            bdst[pos] = d;
        }
    }
}

// ------- degB: per-bucket degree count (LDS) -> deg + dinv, coalesced -------
__global__ __launch_bounds__(256)
void degB_kernel(const int* bdst, const int* bucket_base, int* deg, float* dinv, int N) {
    __shared__ int cur[BSZ];
    int b = blockIdx.x, d0 = b << BSH;
    for (int i = threadIdx.x; i < BSZ; i += 256) cur[i] = 0;
    __syncthreads();
    int e0 = bucket_base[b], e1 = bucket_base[b + 1];
    for (int e = e0 + threadIdx.x; e < e1; e += 256)
        atomicAdd(&cur[bdst[e] - d0], 1);
    __syncthreads();
    for (int i = threadIdx.x; i < BSZ; i += 256) {
        int d = d0 + i;
        if (d < N) {
            int c = cur[i];
            deg[d] = c;
            dinv[d] = (c > 0) ? 1.0f / sqrtf((float)c) : 0.0f;
        }
    }
}

// ---------------- passB: bucket -> csr (LDS cursor, local writes) ----------------
__global__ __launch_bounds__(256)
void passB_kernel(const int* bsrc, const int* bdst, const int* bucket_base,
                  const int* row_start, int* csr) {
    __shared__ int cur[BSZ];
    int b = blockIdx.x, d0 = b << BSH;
    for (int i = threadIdx.x; i < BSZ; i += 256) cur[i] = 0;
    __syncthreads();
    int e0 = bucket_base[b], e1 = bucket_base[b + 1];
    for (int e = e0 + threadIdx.x; e < e1; e += 256) {
        int d = bdst[e];
        int s = bsrc[e];
        int r = atomicAdd(&cur[d - d0], 1);
        csr[row_start[d] + r] = s;
    }
}

// ---------------- exclusive scan over deg (3 kernels) ----------------
__device__ inline int wave_incl_scan(int v, int lane) {
    #pragma unroll
    for (int d = 1; d < 64; d <<= 1) {
        int t = __shfl_up(v, d, 64);
        if (lane >= d) v += t;
    }
    return v;
}

__global__ void scan_block_kernel(const int* deg, int* row_start, int* bsums, int N) {
    __shared__ int wsum[4];
    int t = threadIdx.x, lane = t & 63, wv = t >> 6;
    int i = blockIdx.x * 256 + t;
    int v = (i < N) ? deg[i] : 0;
    int inc = wave_incl_scan(v, lane);
    if (lane == 63) wsum[wv] = inc;
    __syncthreads();
    int off = 0;
    #pragma unroll
    for (int w = 0; w < 4; ++w) if (w < wv) off += wsum[w];
    if (i < N) row_start[i] = off + inc - v;
    if (t == 255) bsums[blockIdx.x] = off + inc;
}

__global__ void scan_sums_kernel(int* bsums, int nb) {
    __shared__ int wsum[8];
    int t = threadIdx.x, lane = t & 63, wv = t >> 6;
    int v = (t < nb) ? bsums[t] : 0;
    int inc = wave_incl_scan(v, lane);
    if (lane == 63) wsum[wv] = inc;
    __syncthreads();
    int off = 0;
    #pragma unroll
    for (int w = 0; w < 8; ++w) if (w < wv) off += wsum[w];
    if (t < nb) bsums[t] = off + inc - v;   // exclusive
}

__global__ void scan_add_kernel(int* row_start, const int* bsums, int N, int E) {
    int i = blockIdx.x * 256 + threadIdx.x;
    if (i < N) row_start[i] += bsums[blockIdx.x];
    if (blockIdx.x == 0 && threadIdx.x == 0) row_start[N] = E;
}

// ------- weight prepack, nt-major: ((nt*KT+kk)*64+lane)*8+j  -------
template<int NT, int KT, int NCOLS>
__global__ void prepack_kernel(const void* W, const int* flags, u16* pack) {
    int p = blockIdx.x * 256 + threadIdx.x;
    constexpr int TOT = NT * KT * 64 * 8;
    if (p >= TOT) return;
    int j = p & 7, lane = (p >> 3) & 63, fk = p >> 9;
    int kk = fk % KT, nt = fk / KT;
    int n = nt * 16 + (lane & 15);
    int k = kk * 32 + (lane >> 4) * 8 + j;
    u16 v = flags[0] ? f2bf(((const float*)W)[k * NCOLS + n])
                     : ((const u16*)W)[k * NCOLS + n];
    pack[p] = v;
}

// ---- gemm1: barrier-free direct-load, N-split. 128 rows x NT*16 cols per block ----
// B (nt-major pack, full NTF cols) -> this block's NT-col slice into 32KB LDS once.
// K-loop fully unrolled, no barriers: A fp32/bf16 loads pipeline across kk.
template<int NT, int NTF, int KT, int G>
__global__ __launch_bounds__(256)
void gemm1_kernel(const void* __restrict__ A, const int* __restrict__ ff,
                  const u16* __restrict__ Bpack, const float* __restrict__ dinv,
                  u16* __restrict__ C, int M) {
    constexpr int K = KT * 32;
    constexpr int Ncols = NTF * 16;
    constexpr int NSPLIT = NTF / NT;
    __shared__ short8 lds[NT * KT * 64];
    const int bh = blockIdx.x % NSPLIT;
    const int bm = blockIdx.x / NSPLIT;
    for (int i = threadIdx.x; i < NT * KT * 64; i += 256) {
        int lane_ = i & 63;
        int kk = (i >> 6) % KT;
        int nt = (i >> 6) / KT;
        lds[i] = ((const short8*)Bpack)[(((bh * NT + nt) * KT) + kk) * 64 + lane_];
    }
    bool fA = (*ff != 0);
    __syncthreads();
    int wave = threadIdx.x >> 6, lane = threadIdx.x & 63;
    int m0 = (bm * 4 + wave) * (16 * G);
    if (m0 >= M) return;
    int q = lane >> 4, l16 = lane & 15;
    int rowc[G];
    #pragma unroll
    for (int g = 0; g < G; ++g) {
        int r = m0 + g * 16 + l16;
        rowc[g] = (r < M) ? r : (M - 1);
    }
    f32x4 acc[G][NT];
    #pragma unroll
    for (int g = 0; g < G; ++g)
        #pragma unroll
        for (int nt = 0; nt < NT; ++nt) acc[g][nt] = (f32x4){0.f, 0.f, 0.f, 0.f};
    #pragma unroll
    for (int kk = 0; kk < KT; ++kk) {
        short8 a[G];
        #pragma unroll
        for (int g = 0; g < G; ++g) {
            if (fA) {
                const float* Af = (const float*)A + (size_t)rowc[g] * K + kk * 32 + q * 8;
                f32x4 v0 = ((const f32x4*)Af)[0];
                f32x4 v1 = ((const f32x4*)Af)[1];
                union { short8 s; u16 u[8]; } pa;
                pa.u[0] = f2bf(v0[0]); pa.u[1] = f2bf(v0[1]);
                pa.u[2] = f2bf(v0[2]); pa.u[3] = f2bf(v0[3]);
                pa.u[4] = f2bf(v1[0]); pa.u[5] = f2bf(v1[1]);
                pa.u[6] = f2bf(v1[2]); pa.u[7] = f2bf(v1[3]);
                a[g] = pa.s;
            } else {
                a[g] = ((const short8*)((const u16*)A + (size_t)rowc[g] * K))[kk * 4 + q];
            }
        }
        #pragma unroll
        for (int nt = 0; nt < NT; ++nt) {
            short8 b = lds[(nt * KT + kk) * 64 + lane];
            #pragma unroll
            for (int g = 0; g < G; ++g)
                acc[g][nt] = __builtin_amdgcn_mfma_f32_16x16x32_bf16(a[g], b, acc[g][nt], 0, 0, 0);
        }
    }
    #pragma unroll
    for (int g = 0; g < G; ++g) {
        float sc[4];
        #pragma unroll
        for (int r = 0; r < 4; ++r) {
            int rr = m0 + g * 16 + q * 4 + r;
            sc[r] = dinv[(rr < M) ? rr : (M - 1)];
        }
        #pragma unroll
        for (int nt = 0; nt < NT; ++nt) {
            int col = bh * (NT * 16) + nt * 16 + l16;
            #pragma unroll
            for (int r = 0; r < 4; ++r) {
                int rrow = m0 + g * 16 + q * 4 + r;
                if (rrow < M)
                    C[(size_t)rrow * Ncols + col] = f2bf(acc[g][nt][r] * sc[r]);
            }
        }
    }
}

// ---- gemm2 (unchanged structure): A bf16 direct, B (nt-major) in LDS ----
template<int NT, int KT, int G>
__global__ __launch_bounds__(256)
void gemm_kernel(const void* __restrict__ A, const int* __restrict__ ff,
                 const u16* __restrict__ Bpack, const float* __restrict__ dinv,
                 u16* __restrict__ C, int M) {
    constexpr int K = KT * 32;
    constexpr int Ncols = NT * 16;
    __shared__ short8 lds[NT * KT * 64];
    for (int i = threadIdx.x; i < NT * KT * 64; i += 256)
        lds[i] = ((const short8*)Bpack)[i];
    bool fA = (*ff != 0);
    __syncthreads();
    int wave = threadIdx.x >> 6, lane = threadIdx.x & 63;
    int m0 = (blockIdx.x * 4 + wave) * (16 * G);
    if (m0 >= M) return;
    int q = lane >> 4;
    int rowc[G];
    #pragma unroll
    for (int g = 0; g < G; ++g) {
        int r = m0 + g * 16 + (lane & 15);
        rowc[g] = (r < M) ? r : (M - 1);
    }
    f32x4 acc[G][NT];
    #pragma unroll
    for (int g = 0; g < G; ++g)
        #pragma unroll
        for (int nt = 0; nt < NT; ++nt) acc[g][nt] = (f32x4){0.f, 0.f, 0.f, 0.f};
    #pragma unroll
    for (int kk = 0; kk < KT; ++kk) {
        short8 a[G];
        #pragma unroll
        for (int g = 0; g < G; ++g) {
            if (fA) {
                const float* Af = (const float*)A + (size_t)rowc[g] * K + kk * 32 + q * 8;
                f32x4 v0 = ((const f32x4*)Af)[0];
                f32x4 v1 = ((const f32x4*)Af)[1];
                union { short8 s; u16 u[8]; } pa;
                pa.u[0] = f2bf(v0[0]); pa.u[1] = f2bf(v0[1]);
                pa.u[2] = f2bf(v0[2]); pa.u[3] = f2bf(v0[3]);
                pa.u[4] = f2bf(v1[0]); pa.u[5] = f2bf(v1[1]);
                pa.u[6] = f2bf(v1[2]); pa.u[7] = f2bf(v1[3]);
                a[g] = pa.s;
            } else {
                a[g] = ((const short8*)((const u16*)A + (size_t)rowc[g] * K))[kk * 4 + q];
            }
        }
        #pragma unroll
        for (int nt = 0; nt < NT; ++nt) {
            short8 b = lds[(nt * KT + kk) * 64 + lane];
            #pragma unroll
            for (int g = 0; g < G; ++g)
                acc[g][nt] = __builtin_amdgcn_mfma_f32_16x16x32_bf16(a[g], b, acc[g][nt], 0, 0, 0);
        }
    }
    #pragma unroll
    for (int g = 0; g < G; ++g) {
        float sc[4];
        #pragma unroll
        for (int r = 0; r < 4; ++r) {
            int rr = m0 + g * 16 + q * 4 + r;
            sc[r] = dinv[(rr < M) ? rr : (M - 1)];
        }
        #pragma unroll
        for (int nt = 0; nt < NT; ++nt) {
            int col = nt * 16 + (lane & 15);
            #pragma unroll
            for (int r = 0; r < 4; ++r) {
                int rrow = m0 + g * 16 + q * 4 + r;
                if (rrow < M)
                    C[(size_t)rrow * Ncols + col] = f2bf(acc[g][nt][r] * sc[r]);
            }
        }
    }
}

// ---- layer-1 aggregation: 8 gathers in flight, packed f32x2 accumulate ----
__global__ __launch_bounds__(256)
void agg1_kernel(const u32* __restrict__ H32, const int* __restrict__ csr,
                 const int* __restrict__ row_start, const float* __restrict__ dinv,
                 const float* __restrict__ b1f, u32* __restrict__ H1, int N) {
    int wave = threadIdx.x >> 6, lane = threadIdx.x & 63;
    int n = blockIdx.x * 4 + wave;
    if (n >= N) return;
    int s0 = row_start[n], s1 = row_start[n + 1];
    f32x2 acc = {0.f, 0.f};
    for (int base = s0; base < s1; base += 64) {
        int m = s1 - base; if (m > 64) m = 64;
        int myidx = (lane < m) ? csr[base + lane] : 0;
        int j = 0;
        for (; j + 8 <= m; j += 8) {
            int i0 = __shfl(myidx, j);
            int i1 = __shfl(myidx, j + 1);
            int i2 = __shfl(myidx, j + 2);
            int i3 = __shfl(myidx, j + 3);
            int i4 = __shfl(myidx, j + 4);
            int i5 = __shfl(myidx, j + 5);
            int i6 = __shfl(myidx, j + 6);
            int i7 = __shfl(myidx, j + 7);
            u32 h0 = H32[(size_t)i0 * 64 + lane];
            u32 h1 = H32[(size_t)i1 * 64 + lane];
            u32 h2 = H32[(size_t)i2 * 64 + lane];
            u32 h3 = H32[(size_t)i3 * 64 + lane];
            u32 h4 = H32[(size_t)i4 * 64 + lane];
            u32 h5 = H32[(size_t)i5 * 64 + lane];
            u32 h6 = H32[(size_t)i6 * 64 + lane];
            u32 h7 = H32[(size_t)i7 * 64 + lane];
            f32x2 t0 = up2(h0) + up2(h1);
            f32x2 t1 = up2(h2) + up2(h3);
            f32x2 t2 = up2(h4) + up2(h5);
            f32x2 t3 = up2(h6) + up2(h7);
            acc += (t0 + t1) + (t2 + t3);
        }
        for (; j + 4 <= m; j += 4) {
            int i0 = __shfl(myidx, j);
            int i1 = __shfl(myidx, j + 1);
            int i2 = __shfl(myidx, j + 2);
            int i3 = __shfl(myidx, j + 3);
            u32 h0 = H32[(size_t)i0 * 64 + lane];
            u32 h1 = H32[(size_t)i1 * 64 + lane];
            u32 h2 = H32[(size_t)i2 * 64 + lane];
            u32 h3 = H32[(size_t)i3 * 64 + lane];
            acc += (up2(h0) + up2(h1)) + (up2(h2) + up2(h3));
        }
        for (; j < m; ++j) {
            int s = __shfl(myidx, j);
            acc += up2(H32[(size_t)s * 64 + lane]);
        }
    }
    float wn = dinv[n];
    float v0 = fmaxf(wn * acc.x + b1f[2 * lane], 0.f);
    float v1 = fmaxf(wn * acc.y + b1f[2 * lane + 1], 0.f);
    H1[(size_t)n * 64 + lane] = (u32)f2bf(v0) | ((u32)f2bf(v1) << 16);
}

// ---- layer-2 aggregation + bias + log_softmax; 8 gathers in flight ----
__global__ __launch_bounds__(256)
void agg2_kernel(const u16* __restrict__ H2, const int* __restrict__ csr,
                 const int* __restrict__ row_start, const float* __restrict__ dinv,
                 const float* __restrict__ b2f, const int* __restrict__ ff,
                 void* __restrict__ out, int N) {
    int half = threadIdx.x >> 5;            // 0..7
    int c = threadIdx.x & 31;
    int n = blockIdx.x * 8 + half;
    if (n >= N) return;
    int s0 = row_start[n], s1 = row_start[n + 1];
    float acc = 0.f;
    for (int base = s0; base < s1; base += 32) {
        int m = s1 - base; if (m > 32) m = 32;
        int myidx = (c < m) ? csr[base + c] : 0;
        int j = 0;
        for (; j + 8 <= m; j += 8) {
            int i0 = __shfl(myidx, j, 32);
            int i1 = __shfl(myidx, j + 1, 32);
            int i2 = __shfl(myidx, j + 2, 32);
            int i3 = __shfl(myidx, j + 3, 32);
            int i4 = __shfl(myidx, j + 4, 32);
            int i5 = __shfl(myidx, j + 5, 32);
            int i6 = __shfl(myidx, j + 6, 32);
            int i7 = __shfl(myidx, j + 7, 32);
            float h0 = bf2f(H2[(size_t)i0 * 32 + c]);
            float h1 = bf2f(H2[(size_t)i1 * 32 + c]);
            float h2 = bf2f(H2[(size_t)i2 * 32 + c]);
            float h3 = bf2f(H2[(size_t)i3 * 32 + c]);
            float h4 = bf2f(H2[(size_t)i4 * 32 + c]);
            float h5 = bf2f(H2[(size_t)i5 * 32 + c]);
            float h6 = bf2f(H2[(size_t)i6 * 32 + c]);
            float h7 = bf2f(H2[(size_t)i7 * 32 + c]);
            acc += ((h0 + h1) + (h2 + h3)) + ((h4 + h5) + (h6 + h7));
        }
        for (; j + 4 <= m; j += 4) {
            int i0 = __shfl(myidx, j, 32);
            int i1 = __shfl(myidx, j + 1, 32);
            int i2 = __shfl(myidx, j + 2, 32);
            int i3 = __shfl(myidx, j + 3, 32);
            float h0 = bf2f(H2[(size_t)i0 * 32 + c]);
            float h1 = bf2f(H2[(size_t)i1 * 32 + c]);
            float h2 = bf2f(H2[(size_t)i2 * 32 + c]);
            float h3 = bf2f(H2[(size_t)i3 * 32 + c]);
            acc += (h0 + h1) + (h2 + h3);
        }
        for (; j < m; ++j) {
            int s = __shfl(myidx, j, 32);
            acc += bf2f(H2[(size_t)s * 32 + c]);
        }
    }
    float tot = dinv[n] * acc + b2f[c];
    float mx = tot;
    #pragma unroll
    for (int m = 16; m; m >>= 1) mx = fmaxf(mx, __shfl_xor(mx, m, 32));
    float ex = expf(tot - mx);
    float sm = ex;
    #pragma unroll
    for (int m = 16; m; m >>= 1) sm += __shfl_xor(sm, m, 32);
    float r = tot - mx - logf(sm);
    if (*ff) ((float*)out)[(size_t)n * 32 + c] = r;
    else     ((u16*)out)[(size_t)n * 32 + c] = f2bf(r);
}

extern "C" void kernel_launch(void* const* d_in, const int* in_sizes, int n_in,
                              void* d_out, int out_size, void* d_ws, size_t ws_size,
                              hipStream_t stream) {
    const void* x  = d_in[0];
    const void* W1 = d_in[1];
    const void* b1 = d_in[2];
    const void* W2 = d_in[3];
    const void* b2 = d_in[4];
    const void* eb = d_in[5];

    const int HID  = in_sizes[2];            // 128
    const int CLS  = in_sizes[4];            // 32
    const int FEAT = in_sizes[1] / HID;      // 256
    const int N    = in_sizes[0] / FEAT;     // 100000
    const int E    = in_sizes[5] / 2;        // 1600000
    const int nb   = (N + BSZ - 1) >> BSH;   // 196 (assumes <= 256)
    (void)n_in; (void)out_size;

    char* w = (char*)d_ws;
    size_t p = 0;
    auto alloc = [&](size_t bytes) {
        size_t o = p; p = (p + bytes + 255) & ~(size_t)255; return o;
    };
    int*   flags      = (int*)  (w + alloc(32));
    int*   deg        = (int*)  (w + alloc((size_t)N * 4));
    int*   row_start  = (int*)  (w + alloc((size_t)(N + 1) * 4));
    int*   bsums      = (int*)  (w + alloc(512 * 4));
    int*   bucket_cnt = (int*)  (w + alloc(257 * 4));
    int*   bucket_base= (int*)  (w + alloc(257 * 4));
    int*   bucket_rsv = (int*)  (w + alloc(256 * 4));
    int*   bsrc       = (int*)  (w + alloc((size_t)E * 4));
    int*   bdst       = (int*)  (w + alloc((size_t)E * 4));
    int*   csr        = (int*)  (w + alloc((size_t)E * 4));
    float* dinv       = (float*)(w + alloc((size_t)N * 4));
    float* b1f        = (float*)(w + alloc((size_t)HID * 4));
    float* b2f        = (float*)(w + alloc((size_t)CLS * 4));
    u16*   B1p        = (u16*)  (w + alloc((size_t)FEAT * HID * 2));
    u16*   B2p        = (u16*)  (w + alloc((size_t)HID * CLS * 2));
    u16*   H          = (u16*)  (w + alloc((size_t)N * HID * 2));
    u16*   H1         = (u16*)  (w + alloc((size_t)N * HID * 2));
    u16*   H2         = (u16*)  (w + alloc((size_t)N * CLS * 2));
    if (p > ws_size) return;   // workspace too small: fail visibly

    detect_kernel<<<1, 256, 0, stream>>>((const u32*)x, (const int*)eb, flags);
    hipMemsetAsync(bucket_cnt, 0, 257 * 4, stream);
    bconv_kernel<<<1, 256, 0, stream>>>(b1, b2, flags, b1f, b2f, HID, CLS);

    hist_kernel<<<(E + 4095) / 4096, 256, 0, stream>>>(eb, flags, bucket_cnt, E, nb);
    bucket_scan_kernel<<<1, 256, 0, stream>>>(bucket_cnt, bucket_base, bucket_rsv, nb, E);
    passA_kernel<<<(E + 8191) / 8192, 256, 0, stream>>>(eb, flags, bucket_rsv,
                                                        bsrc, bdst, E, nb);
    degB_kernel<<<nb, 256, 0, stream>>>(bdst, bucket_base, deg, dinv, N);

    int nsb = (N + 255) / 256;
    scan_block_kernel<<<nsb, 256, 0, stream>>>(deg, row_start, bsums, N);
    scan_sums_kernel<<<1, 512, 0, stream>>>(bsums, nsb);
    scan_add_kernel<<<nsb, 256, 0, stream>>>(row_start, bsums, N, E);

    passB_kernel<<<nb, 256, 0, stream>>>(bsrc, bdst, bucket_base, row_start, csr);

    prepack_kernel<8, 8, 128><<<(8 * 8 * 64 * 8 + 255) / 256, 256, 0, stream>>>(W1, flags, B1p);
    prepack_kernel<2, 4, 32><<<(2 * 4 * 64 * 8 + 255) / 256, 256, 0, stream>>>(W2, flags, B2p);

    // gemm1: barrier-free, N-split in 2 col-halves (NT=4 of NTF=8), 128-row stripes
    gemm1_kernel<4, 8, 8, 2><<<2 * ((N + 127) / 128), 256, 0, stream>>>(x, flags, B1p, dinv, H, N);
    agg1_kernel<<<(N + 3) / 4, 256, 0, stream>>>((const u32*)H, csr, row_start, dinv, b1f,
                                                 (u32*)H1, N);
    gemm_kernel<2, 4, 2><<<(N + 127) / 128, 256, 0, stream>>>(H1, flags + 1, B2p, dinv, H2, N);
    agg2_kernel<<<(N + 7) / 8, 256, 0, stream>>>(H2, csr, row_start, dinv, b2f, flags,
                                                 (void*)d_out, N);
}

// Round 9
// 371.443 us; speedup vs baseline: 1.7065x; 1.0496x over previous
//
#include <hip/hip_runtime.h>

typedef unsigned short u16;
typedef unsigned int   u32;
typedef __attribute__((ext_vector_type(8))) short short8;
typedef __attribute__((ext_vector_type(4))) float f32x4;
typedef __attribute__((ext_vector_type(2))) float f32x2;

constexpr int BSH = 9;               // bucket = dst >> 9  (512 dsts/bucket)
constexpr int BSZ = 1 << BSH;

__device__ inline float bf2f(u32 bits16) {
    union { u32 u; float f; } c; c.u = bits16 << 16; return c.f;
}
// round-half-up bf16 (cheap: add + shift); |err| <= 0.5 ulp like RNE
__device__ inline u16 f2bf(float f) {
    union { float f; u32 u; } c; c.f = f;
    return (u16)((c.u + 0x8000u) >> 16);
}
// unpack bf16-pair word into float2 (lo, hi)
__device__ inline f32x2 up2(u32 h) {
    union { u32 u[2]; f32x2 f; } c;
    c.u[0] = h << 16;
    c.u[1] = h & 0xffff0000u;
    return c.f;
}
__device__ inline int ld_edge(const void* eb, int f64, size_t idx) {
    return f64 ? (int)((const long long*)eb)[idx] : ((const int*)eb)[idx];
}

// ---------------- dtype detect + bucket cursor init ----------------
__global__ void detect_kernel(const u32* xw, const int* ebuf_int, int* flags,
                              int* bucket_rsv, int nb, int CAP) {
    __shared__ int cnt;
    if (threadIdx.x == 0) cnt = 0;
    __syncthreads();
    u32 w = xw[threadIdx.x];
    int e = (int)((w >> 7) & 0xffu);
    if (e >= 110 && e <= 145) atomicAdd(&cnt, 1);
    int ev = ebuf_int[2 * threadIdx.x + 1];
    unsigned long long any = __ballot(ev != 0);
    if ((int)threadIdx.x < nb) bucket_rsv[threadIdx.x] = threadIdx.x * CAP;
    __syncthreads();
    if (threadIdx.x == 0) {
        flags[0] = (cnt < 192) ? 1 : 0;
        flags[1] = 0;
        flags[2] = (any == 0ULL) ? 1 : 0;
    }
}

// ---------------- bias convert to fp32 ----------------
__global__ void bconv_kernel(const void* b1, const void* b2, const int* flags,
                             float* b1f, float* b2f, int HID, int CLS) {
    int i = blockIdx.x * 256 + threadIdx.x;
    int f = flags[0];
    if (i < HID) b1f[i] = f ? ((const float*)b1)[i] : bf2f(((const u16*)b1)[i]);
    if (i < CLS) b2f[i] = f ? ((const float*)b2)[i] : bf2f(((const u16*)b2)[i]);
}

// ---- passA: single pass, scatter (src,dst) pairs into fixed-cap dst-buckets ----
__global__ __launch_bounds__(256)
void passA_kernel(const void* eb, const int* flags, int* bucket_rsv,
                  int2* bpair, int E, int nb, int CAP) {
    __shared__ int hist[256];
    __shared__ int rbase[256];
    hist[threadIdx.x] = 0;
    __syncthreads();
    int f64 = flags[2];
    int base = blockIdx.x * 8192;
    #pragma unroll
    for (int k = 0; k < 32; ++k) {
        int e = base + k * 256 + threadIdx.x;
        if (e < E) {
            int d = ld_edge(eb, f64, (size_t)E + e);
            atomicAdd(&hist[d >> BSH], 1);
        }
    }
    __syncthreads();
    {
        int b = threadIdx.x;
        int c = (b < nb) ? hist[b] : 0;
        rbase[b] = c ? atomicAdd(&bucket_rsv[b], c) : 0;
        hist[b] = 0;
    }
    __syncthreads();
    #pragma unroll
    for (int k = 0; k < 32; ++k) {
        int e = base + k * 256 + threadIdx.x;
        if (e < E) {
            int d = ld_edge(eb, f64, (size_t)E + e);
            int s = ld_edge(eb, f64, (size_t)e);
            int bb = d >> BSH;
            int r = atomicAdd(&hist[bb], 1);
            int pos = rbase[bb] + r;
            if (pos < (bb + 1) * CAP)          // overflow guard (never for random)
                bpair[pos] = make_int2(s, d);
        }
    }
}

// ---- fillscan: bucket fills -> exclusive scan -> bucket_base; row_start[N]=E ----
__global__ void fillscan_kernel(const int* bucket_rsv, int* bucket_base,
                                int* row_start, int nb, int E, int N, int CAP) {
    __shared__ int wsum[4];
    int t = threadIdx.x, lane = t & 63, wv = t >> 6;
    int v = (t < nb) ? (bucket_rsv[t] - t * CAP) : 0;
    int inc = v;
    #pragma unroll
    for (int d = 1; d < 64; d <<= 1) {
        int tmp = __shfl_up(inc, d, 64);
        if (lane >= d) inc += tmp;
    }
    if (lane == 63) wsum[wv] = inc;
    __syncthreads();
    int off = 0;
    #pragma unroll
    for (int w = 0; w < 4; ++w) if (w < wv) off += wsum[w];
    int excl = off + inc - v;
    if (t <= nb) bucket_base[t] = (t == nb) ? E : excl;
    if (t == 0) row_start[N] = E;
}

// ---- bucketF: per-bucket degree count + local scan -> dinv,row_start,csr ----
__global__ __launch_bounds__(256)
void bucketF_kernel(const int2* __restrict__ bpair, const int* __restrict__ bucket_rsv,
                    const int* __restrict__ bucket_base, float* __restrict__ dinv,
                    int* __restrict__ row_start, int* __restrict__ csr, int N, int CAP) {
    __shared__ int lcnt[BSZ];
    __shared__ int lrow[BSZ];
    __shared__ int wsum[4];
    int b = blockIdx.x, d0 = b << BSH;
    int t = threadIdx.x, lane = t & 63, wv = t >> 6;
    lcnt[2 * t] = 0; lcnt[2 * t + 1] = 0;
    __syncthreads();
    int e0 = b * CAP;
    int e1 = bucket_rsv[b];
    for (int e = e0 + t; e < e1; e += 256)
        atomicAdd(&lcnt[bpair[e].y - d0], 1);
    __syncthreads();
    int c0 = lcnt[2 * t], c1 = lcnt[2 * t + 1];
    int p = c0 + c1;
    int inc = p;
    #pragma unroll
    for (int d = 1; d < 64; d <<= 1) {
        int tmp = __shfl_up(inc, d, 64);
        if (lane >= d) inc += tmp;
    }
    if (lane == 63) wsum[wv] = inc;
    __syncthreads();
    int off = 0;
    #pragma unroll
    for (int w = 0; w < 4; ++w) if (w < wv) off += wsum[w];
    int ex0 = off + inc - p;                 // exclusive prefix for element 2t
    int bb = bucket_base[b];
    lrow[2 * t] = ex0;
    lrow[2 * t + 1] = ex0 + c0;
    int da = d0 + 2 * t, db = d0 + 2 * t + 1;
    if (da < N) { row_start[da] = bb + ex0;      dinv[da] = c0 ? rsqrtf((float)c0) : 0.f; }
    if (db < N) { row_start[db] = bb + ex0 + c0; dinv[db] = c1 ? rsqrtf((float)c1) : 0.f; }
    lcnt[2 * t] = 0; lcnt[2 * t + 1] = 0;    // reuse as cursor
    __syncthreads();
    for (int e = e0 + t; e < e1; e += 256) {
        int2 pr = bpair[e];
        int li = pr.y - d0;
        int r = atomicAdd(&lcnt[li], 1);
        csr[bb + lrow[li] + r] = pr.x;
    }
}

// ------- weight prepack, nt-major: ((nt*KT+kk)*64+lane)*8+j  -------
template<int NT, int KT, int NCOLS>
__global__ void prepack_kernel(const void* W, const int* flags, u16* pack) {
    int p = blockIdx.x * 256 + threadIdx.x;
    constexpr int TOT = NT * KT * 64 * 8;
    if (p >= TOT) return;
    int j = p & 7, lane = (p >> 3) & 63, fk = p >> 9;
    int kk = fk % KT, nt = fk / KT;
    int n = nt * 16 + (lane & 15);
    int k = kk * 32 + (lane >> 4) * 8 + j;
    u16 v = flags[0] ? f2bf(((const float*)W)[k * NCOLS + n])
                     : ((const u16*)W)[k * NCOLS + n];
    pack[p] = v;
}

// ---- gemm1: barrier-free direct-load, N-split (unchanged from round 8) ----
template<int NT, int NTF, int KT, int G>
__global__ __launch_bounds__(256)
void gemm1_kernel(const void* __restrict__ A, const int* __restrict__ ff,
                  const u16* __restrict__ Bpack, const float* __restrict__ dinv,
                  u16* __restrict__ C, int M) {
    constexpr int K = KT * 32;
    constexpr int Ncols = NTF * 16;
    constexpr int NSPLIT = NTF / NT;
    __shared__ short8 lds[NT * KT * 64];
    const int bh = blockIdx.x % NSPLIT;
    const int bm = blockIdx.x / NSPLIT;
    for (int i = threadIdx.x; i < NT * KT * 64; i += 256) {
        int lane_ = i & 63;
        int kk = (i >> 6) % KT;
        int nt = (i >> 6) / KT;
        lds[i] = ((const short8*)Bpack)[(((bh * NT + nt) * KT) + kk) * 64 + lane_];
    }
    bool fA = (*ff != 0);
    __syncthreads();
    int wave = threadIdx.x >> 6, lane = threadIdx.x & 63;
    int m0 = (bm * 4 + wave) * (16 * G);
    if (m0 >= M) return;
    int q = lane >> 4, l16 = lane & 15;
    int rowc[G];
    #pragma unroll
    for (int g = 0; g < G; ++g) {
        int r = m0 + g * 16 + l16;
        rowc[g] = (r < M) ? r : (M - 1);
    }
    f32x4 acc[G][NT];
    #pragma unroll
    for (int g = 0; g < G; ++g)
        #pragma unroll
        for (int nt = 0; nt < NT; ++nt) acc[g][nt] = (f32x4){0.f, 0.f, 0.f, 0.f};
    #pragma unroll
    for (int kk = 0; kk < KT; ++kk) {
        short8 a[G];
        #pragma unroll
        for (int g = 0; g < G; ++g) {
            if (fA) {
                const float* Af = (const float*)A + (size_t)rowc[g] * K + kk * 32 + q * 8;
                f32x4 v0 = ((const f32x4*)Af)[0];
                f32x4 v1 = ((const f32x4*)Af)[1];
                union { short8 s; u16 u[8]; } pa;
                pa.u[0] = f2bf(v0[0]); pa.u[1] = f2bf(v0[1]);
                pa.u[2] = f2bf(v0[2]); pa.u[3] = f2bf(v0[3]);
                pa.u[4] = f2bf(v1[0]); pa.u[5] = f2bf(v1[1]);
                pa.u[6] = f2bf(v1[2]); pa.u[7] = f2bf(v1[3]);
                a[g] = pa.s;
            } else {
                a[g] = ((const short8*)((const u16*)A + (size_t)rowc[g] * K))[kk * 4 + q];
            }
        }
        #pragma unroll
        for (int nt = 0; nt < NT; ++nt) {
            short8 b = lds[(nt * KT + kk) * 64 + lane];
            #pragma unroll
            for (int g = 0; g < G; ++g)
                acc[g][nt] = __builtin_amdgcn_mfma_f32_16x16x32_bf16(a[g], b, acc[g][nt], 0, 0, 0);
        }
    }
    #pragma unroll
    for (int g = 0; g < G; ++g) {
        float sc[4];
        #pragma unroll
        for (int r = 0; r < 4; ++r) {
            int rr = m0 + g * 16 + q * 4 + r;
            sc[r] = dinv[(rr < M) ? rr : (M - 1)];
        }
        #pragma unroll
        for (int nt = 0; nt < NT; ++nt) {
            int col = bh * (NT * 16) + nt * 16 + l16;
            #pragma unroll
            for (int r = 0; r < 4; ++r) {
                int rrow = m0 + g * 16 + q * 4 + r;
                if (rrow < M)
                    C[(size_t)rrow * Ncols + col] = f2bf(acc[g][nt][r] * sc[r]);
            }
        }
    }
}

// ---- gemm2 (unchanged): A bf16 direct, B (nt-major) in LDS ----
template<int NT, int KT, int G>
__global__ __launch_bounds__(256)
void gemm_kernel(const void* __restrict__ A, const int* __restrict__ ff,
                 const u16* __restrict__ Bpack, const float* __restrict__ dinv,
                 u16* __restrict__ C, int M) {
    constexpr int K = KT * 32;
    constexpr int Ncols = NT * 16;
    __shared__ short8 lds[NT * KT * 64];
    for (int i = threadIdx.x; i < NT * KT * 64; i += 256)
        lds[i] = ((const short8*)Bpack)[i];
    bool fA = (*ff != 0);
    __syncthreads();
    int wave = threadIdx.x >> 6, lane = threadIdx.x & 63;
    int m0 = (blockIdx.x * 4 + wave) * (16 * G);
    if (m0 >= M) return;
    int q = lane >> 4;
    int rowc[G];
    #pragma unroll
    for (int g = 0; g < G; ++g) {
        int r = m0 + g * 16 + (lane & 15);
        rowc[g] = (r < M) ? r : (M - 1);
    }
    f32x4 acc[G][NT];
    #pragma unroll
    for (int g = 0; g < G; ++g)
        #pragma unroll
        for (int nt = 0; nt < NT; ++nt) acc[g][nt] = (f32x4){0.f, 0.f, 0.f, 0.f};
    #pragma unroll
    for (int kk = 0; kk < KT; ++kk) {
        short8 a[G];
        #pragma unroll
        for (int g = 0; g < G; ++g) {
            if (fA) {
                const float* Af = (const float*)A + (size_t)rowc[g] * K + kk * 32 + q * 8;
                f32x4 v0 = ((const f32x4*)Af)[0];
                f32x4 v1 = ((const f32x4*)Af)[1];
                union { short8 s; u16 u[8]; } pa;
                pa.u[0] = f2bf(v0[0]); pa.u[1] = f2bf(v0[1]);
                pa.u[2] = f2bf(v0[2]); pa.u[3] = f2bf(v0[3]);
                pa.u[4] = f2bf(v1[0]); pa.u[5] = f2bf(v1[1]);
                pa.u[6] = f2bf(v1[2]); pa.u[7] = f2bf(v1[3]);
                a[g] = pa.s;
            } else {
                a[g] = ((const short8*)((const u16*)A + (size_t)rowc[g] * K))[kk * 4 + q];
            }
        }
        #pragma unroll
        for (int nt = 0; nt < NT; ++nt) {
            short8 b = lds[(nt * KT + kk) * 64 + lane];
            #pragma unroll
            for (int g = 0; g < G; ++g)
                acc[g][nt] = __builtin_amdgcn_mfma_f32_16x16x32_bf16(a[g], b, acc[g][nt], 0, 0, 0);
        }
    }
    #pragma unroll
    for (int g = 0; g < G; ++g) {
        float sc[4];
        #pragma unroll
        for (int r = 0; r < 4; ++r) {
            int rr = m0 + g * 16 + q * 4 + r;
            sc[r] = dinv[(rr < M) ? rr : (M - 1)];
        }
        #pragma unroll
        for (int nt = 0; nt < NT; ++nt) {
            int col = nt * 16 + (lane & 15);
            #pragma unroll
            for (int r = 0; r < 4; ++r) {
                int rrow = m0 + g * 16 + q * 4 + r;
                if (rrow < M)
                    C[(size_t)rrow * Ncols + col] = f2bf(acc[g][nt][r] * sc[r]);
            }
        }
    }
}

// ---- layer-1 aggregation (unchanged): 8 gathers in flight, packed f32x2 ----
__global__ __launch_bounds__(256)
void agg1_kernel(const u32* __restrict__ H32, const int* __restrict__ csr,
                 const int* __restrict__ row_start, const float* __restrict__ dinv,
                 const float* __restrict__ b1f, u32* __restrict__ H1, int N) {
    int wave = threadIdx.x >> 6, lane = threadIdx.x & 63;
    int n = blockIdx.x * 4 + wave;
    if (n >= N) return;
    int s0 = row_start[n], s1 = row_start[n + 1];
    f32x2 acc = {0.f, 0.f};
    for (int base = s0; base < s1; base += 64) {
        int m = s1 - base; if (m > 64) m = 64;
        int myidx = (lane < m) ? csr[base + lane] : 0;
        int j = 0;
        for (; j + 8 <= m; j += 8) {
            int i0 = __shfl(myidx, j);
            int i1 = __shfl(myidx, j + 1);
            int i2 = __shfl(myidx, j + 2);
            int i3 = __shfl(myidx, j + 3);
            int i4 = __shfl(myidx, j + 4);
            int i5 = __shfl(myidx, j + 5);
            int i6 = __shfl(myidx, j + 6);
            int i7 = __shfl(myidx, j + 7);
            u32 h0 = H32[(size_t)i0 * 64 + lane];
            u32 h1 = H32[(size_t)i1 * 64 + lane];
            u32 h2 = H32[(size_t)i2 * 64 + lane];
            u32 h3 = H32[(size_t)i3 * 64 + lane];
            u32 h4 = H32[(size_t)i4 * 64 + lane];
            u32 h5 = H32[(size_t)i5 * 64 + lane];
            u32 h6 = H32[(size_t)i6 * 64 + lane];
            u32 h7 = H32[(size_t)i7 * 64 + lane];
            f32x2 t0 = up2(h0) + up2(h1);
            f32x2 t1 = up2(h2) + up2(h3);
            f32x2 t2 = up2(h4) + up2(h5);
            f32x2 t3 = up2(h6) + up2(h7);
            acc += (t0 + t1) + (t2 + t3);
        }
        for (; j + 4 <= m; j += 4) {
            int i0 = __shfl(myidx, j);
            int i1 = __shfl(myidx, j + 1);
            int i2 = __shfl(myidx, j + 2);
            int i3 = __shfl(myidx, j + 3);
            u32 h0 = H32[(size_t)i0 * 64 + lane];
            u32 h1 = H32[(size_t)i1 * 64 + lane];
            u32 h2 = H32[(size_t)i2 * 64 + lane];
            u32 h3 = H32[(size_t)i3 * 64 + lane];
            acc += (up2(h0) + up2(h1)) + (up2(h2) + up2(h3));
        }
        for (; j < m; ++j) {
            int s = __shfl(myidx, j);
            acc += up2(H32[(size_t)s * 64 + lane]);
        }
    }
    float wn = dinv[n];
    float v0 = fmaxf(wn * acc.x + b1f[2 * lane], 0.f);
    float v1 = fmaxf(wn * acc.y + b1f[2 * lane + 1], 0.f);
    H1[(size_t)n * 64 + lane] = (u32)f2bf(v0) | ((u32)f2bf(v1) << 16);
}

// ---- layer-2 aggregation + log_softmax: wave/node, 16 lanes/edge, u32 loads ----
// lane = (grp 0..3, l16 0..15); lane handles classes 2*l16, 2*l16+1 of edge grp
__global__ __launch_bounds__(256)
void agg2_kernel(const u32* __restrict__ H2, const int* __restrict__ csr,
                 const int* __restrict__ row_start, const float* __restrict__ dinv,
                 const float* __restrict__ b2f, const int* __restrict__ ff,
                 void* __restrict__ out, int N) {
    int wave = threadIdx.x >> 6, lane = threadIdx.x & 63;
    int n = blockIdx.x * 4 + wave;
    if (n >= N) return;
    int l16 = lane & 15, grp = lane >> 4;
    int s0 = row_start[n], s1 = row_start[n + 1];
    f32x2 acc = {0.f, 0.f};
    for (int base = s0; base < s1; base += 64) {
        int m = s1 - base; if (m > 64) m = 64;
        int myidx = (lane < m) ? csr[base + lane] : 0;
        int j = 0;
        for (; j + 8 <= m; j += 8) {
            int ia = __shfl(myidx, j + grp);
            int ib = __shfl(myidx, j + 4 + grp);
            u32 ha = H2[(size_t)ia * 16 + l16];
            u32 hb = H2[(size_t)ib * 16 + l16];
            acc += up2(ha) + up2(hb);
        }
        for (; j < m; j += 4) {
            int jj = j + grp;
            int iv = __shfl(myidx, (jj < m) ? jj : 0);
            if (jj < m) acc += up2(H2[(size_t)iv * 16 + l16]);
        }
    }
    // reduce across the 4 edge-groups (lanes l16, l16+16, l16+32, l16+48)
    acc.x += __shfl_xor(acc.x, 16); acc.y += __shfl_xor(acc.y, 16);
    acc.x += __shfl_xor(acc.x, 32); acc.y += __shfl_xor(acc.y, 32);
    float wn = dinv[n];
    f32x2 tot;
    tot.x = wn * acc.x + b2f[2 * l16];
    tot.y = wn * acc.y + b2f[2 * l16 + 1];
    float mx = fmaxf(tot.x, tot.y);
    #pragma unroll
    for (int msk = 8; msk; msk >>= 1) mx = fmaxf(mx, __shfl_xor(mx, msk));
    float ex = expf(tot.x - mx) + expf(tot.y - mx);
    #pragma unroll
    for (int msk = 8; msk; msk >>= 1) ex += __shfl_xor(ex, msk);
    float ls = mx + logf(ex);
    if (grp == 0) {
        if (*ff) {
            f32x2 r; r.x = tot.x - ls; r.y = tot.y - ls;
            ((f32x2*)out)[(size_t)n * 16 + l16] = r;
        } else {
            ((u32*)out)[(size_t)n * 16 + l16] =
                (u32)f2bf(tot.x - ls) | ((u32)f2bf(tot.y - ls) << 16);
        }
    }
}

extern "C" void kernel_launch(void* const* d_in, const int* in_sizes, int n_in,
                              void* d_out, int out_size, void* d_ws, size_t ws_size,
                              hipStream_t stream) {
    const void* x  = d_in[0];
    const void* W1 = d_in[1];
    const void* b1 = d_in[2];
    const void* W2 = d_in[3];
    const void* b2 = d_in[4];
    const void* eb = d_in[5];

    const int HID  = in_sizes[2];            // 128
    const int CLS  = in_sizes[4];            // 32
    const int FEAT = in_sizes[1] / HID;      // 256
    const int N    = in_sizes[0] / FEAT;     // 100000
    const int E    = in_sizes[5] / 2;        // 1600000
    const int nb   = (N + BSZ - 1) >> BSH;   // 196 (assumes <= 256)
    const int CAP  = (((4 * (E / nb)) >> 10) + 2) << 10;   // ~4x avg fill, 1K-rounded
    (void)n_in; (void)out_size;

    char* w = (char*)d_ws;
    size_t p = 0;
    auto alloc = [&](size_t bytes) {
        size_t o = p; p = (p + bytes + 255) & ~(size_t)255; return o;
    };
    int*   flags      = (int*)  (w + alloc(32));
    int*   row_start  = (int*)  (w + alloc((size_t)(N + 1) * 4));
    int*   bucket_base= (int*)  (w + alloc(257 * 4));
    int*   bucket_rsv = (int*)  (w + alloc(256 * 4));
    int2*  bpair      = (int2*) (w + alloc((size_t)nb * CAP * 8));
    int*   csr        = (int*)  (w + alloc((size_t)E * 4));
    float* dinv       = (float*)(w + alloc((size_t)N * 4));
    float* b1f        = (float*)(w + alloc((size_t)HID * 4));
    float* b2f        = (float*)(w + alloc((size_t)CLS * 4));
    u16*   B1p        = (u16*)  (w + alloc((size_t)FEAT * HID * 2));
    u16*   B2p        = (u16*)  (w + alloc((size_t)HID * CLS * 2));
    u16*   H          = (u16*)  (w + alloc((size_t)N * HID * 2));
    u16*   H1         = (u16*)  (w + alloc((size_t)N * HID * 2));
    u16*   H2         = (u16*)  (w + alloc((size_t)N * CLS * 2));
    if (p > ws_size) return;   // workspace too small: fail visibly

    detect_kernel<<<1, 256, 0, stream>>>((const u32*)x, (const int*)eb, flags,
                                         bucket_rsv, nb, CAP);
    bconv_kernel<<<1, 256, 0, stream>>>(b1, b2, flags, b1f, b2f, HID, CLS);

    passA_kernel<<<(E + 8191) / 8192, 256, 0, stream>>>(eb, flags, bucket_rsv,
                                                        bpair, E, nb, CAP);
    fillscan_kernel<<<1, 256, 0, stream>>>(bucket_rsv, bucket_base, row_start,
                                           nb, E, N, CAP);
    bucketF_kernel<<<nb, 256, 0, stream>>>(bpair, bucket_rsv, bucket_base,
                                           dinv, row_start, csr, N, CAP);

    prepack_kernel<8, 8, 128><<<(8 * 8 * 64 * 8 + 255) / 256, 256, 0, stream>>>(W1, flags, B1p);
    prepack_kernel<2, 4, 32><<<(2 * 4 * 64 * 8 + 255) / 256, 256, 0, stream>>>(W2, flags, B2p);

    // gemm1: barrier-free, N-split in 2 col-halves (NT=4 of NTF=8), 128-row stripes
    gemm1_kernel<4, 8, 8, 2><<<2 * ((N + 127) / 128), 256, 0, stream>>>(x, flags, B1p, dinv, H, N);
    agg1_kernel<<<(N + 3) / 4, 256, 0, stream>>>((const u32*)H, csr, row_start, dinv, b1f,
                                                 (u32*)H1, N);
    gemm_kernel<2, 4, 2><<<(N + 127) / 128, 256, 0, stream>>>(H1, flags + 1, B2p, dinv, H2, N);
    agg2_kernel<<<(N + 3) / 4, 256, 0, stream>>>((const u32*)H2, csr, row_start, dinv, b2f,
                                                 flags, (void*)d_out, N);
}